// Round 1
// 302.699 us; speedup vs baseline: 1.0038x; 1.0038x over previous
//
#include <hip/hip_runtime.h>

constexpr int NB    = 8;     // batches
constexpr int NN    = 256;   // sequence length
constexpr int F0    = 512;
constexpr int F1    = 256;
constexpr int F2    = 128;
constexpr int ROWS  = NB * NN;   // 2048
constexpr int KMAX  = 30;
constexpr float INF = 1e30f;

// ---------------- fp32 GEMM: C = act(A @ B + bias), 64x32 tile, BK=16 ----------
__global__ __launch_bounds__(256) void gemm_bias_act(
    const float* __restrict__ A, const float* __restrict__ B,
    const float* __restrict__ bias, float* __restrict__ C,
    int M, int Ncols, int K, int relu)
{
  __shared__ float As[16][64];   // [k][m]
  __shared__ float Bs[16][32];   // [k][n]
  const int tid = threadIdx.x;
  const int tx = tid & 15;       // col group  (2 cols)
  const int ty = tid >> 4;       // row group  (4 rows)
  const int rowBase = blockIdx.y * 64;
  const int colBase = blockIdx.x * 32;
  float acc[4][2] = {};
  for (int k0 = 0; k0 < K; k0 += 16) {
    {
      const int r  = tid >> 2;
      const int kq = (tid & 3) << 2;
      const float4 av = *(const float4*)(A + (size_t)(rowBase + r) * K + (k0 + kq));
      As[kq+0][r] = av.x; As[kq+1][r] = av.y; As[kq+2][r] = av.z; As[kq+3][r] = av.w;
      const int kr = tid >> 4;
      const int c2 = (tid & 15) << 1;
      const float2 bv = *(const float2*)(B + (size_t)(k0 + kr) * Ncols + (colBase + c2));
      Bs[kr][c2+0] = bv.x; Bs[kr][c2+1] = bv.y;
    }
    __syncthreads();
    #pragma unroll
    for (int kk = 0; kk < 16; kk++) {
      const float4 a = *(const float4*)&As[kk][ty*4];
      const float b0v = Bs[kk][tx*2+0];
      const float b1v = Bs[kk][tx*2+1];
      acc[0][0] += a.x*b0v; acc[0][1] += a.x*b1v;
      acc[1][0] += a.y*b0v; acc[1][1] += a.y*b1v;
      acc[2][0] += a.z*b0v; acc[2][1] += a.z*b1v;
      acc[3][0] += a.w*b0v; acc[3][1] += a.w*b1v;
    }
    __syncthreads();
  }
  #pragma unroll
  for (int i = 0; i < 4; i++) {
    const int rr = rowBase + ty*4 + i;
    #pragma unroll
    for (int j = 0; j < 2; j++) {
      const int cc = colBase + tx*2 + j;
      float v = acc[i][j] + bias[cc];
      if (relu) v = fmaxf(v, 0.0f);
      C[(size_t)rr * Ncols + cc] = v;
    }
  }
}

// ---------------- row norms: norms[r] = ||z_r||^2, one wave per row ------------
__global__ __launch_bounds__(256) void row_norms(
    const float* __restrict__ z, float* __restrict__ norms)
{
  const int wave = (blockIdx.x * blockDim.x + threadIdx.x) >> 6;
  const int lane = threadIdx.x & 63;
  if (wave >= ROWS) return;
  const float* p = z + (size_t)wave * F2;
  float a = p[lane], b = p[lane + 64];
  float v = a*a + b*b;
  #pragma unroll
  for (int d = 32; d; d >>= 1) v += __shfl_xor(v, d);
  if (lane == 0) norms[wave] = v;
}

// ---------------- D[b,n,m] = 0.5*(1 - (z_n.z_m)/sqrt(max(|z_n|^2|z_m|^2,1e-8)))
__global__ __launch_bounds__(256) void corr_dist(
    const float* __restrict__ z, const float* __restrict__ norms,
    float* __restrict__ D)
{
  const int b = blockIdx.z;
  const float* zb = z + (size_t)b * NN * F2;
  __shared__ float As[16][64];  // [k][row]
  __shared__ float Bs[16][64];  // [k][col]
  const int tid = threadIdx.x;
  const int tx = tid & 15;
  const int ty = tid >> 4;
  const int rowBase = blockIdx.y * 64;
  const int colBase = blockIdx.x * 64;
  float acc[4][4] = {};
  for (int k0 = 0; k0 < F2; k0 += 16) {
    {
      const int r  = tid >> 2;
      const int kq = (tid & 3) << 2;
      const float4 av = *(const float4*)(zb + (size_t)(rowBase + r) * F2 + (k0 + kq));
      As[kq+0][r] = av.x; As[kq+1][r] = av.y; As[kq+2][r] = av.z; As[kq+3][r] = av.w;
      const float4 bv = *(const float4*)(zb + (size_t)(colBase + r) * F2 + (k0 + kq));
      Bs[kq+0][r] = bv.x; Bs[kq+1][r] = bv.y; Bs[kq+2][r] = bv.z; Bs[kq+3][r] = bv.w;
    }
    __syncthreads();
    #pragma unroll
    for (int kk = 0; kk < 16; kk++) {
      const float4 a = *(const float4*)&As[kk][ty*4];
      const float4 bq = *(const float4*)&Bs[kk][tx*4];
      const float ar[4] = {a.x, a.y, a.z, a.w};
      const float br[4] = {bq.x, bq.y, bq.z, bq.w};
      #pragma unroll
      for (int i = 0; i < 4; i++)
        #pragma unroll
        for (int j = 0; j < 4; j++)
          acc[i][j] += ar[i] * br[j];
    }
    __syncthreads();
  }
  float* Db = D + (size_t)b * NN * NN;
  #pragma unroll
  for (int i = 0; i < 4; i++) {
    const int rr = rowBase + ty*4 + i;
    const float nr = norms[b*NN + rr];
    #pragma unroll
    for (int j = 0; j < 4; j++) {
      const int cc = colBase + tx*4 + j;
      const float nc = norms[b*NN + cc];
      const float denom = sqrtf(fmaxf(nr * nc, 1e-8f));
      Db[(size_t)rr * NN + cc] = 0.5f * (1.0f - acc[i][j] / denom);
    }
  }
}

// ---------------- row-wise fp64 inclusive scan: one wave per row ----------------
__global__ __launch_bounds__(256) void rowscan(
    const float* __restrict__ D, double* __restrict__ S)
{
  const int r = blockIdx.x * 4 + (threadIdx.x >> 6);   // 2048 rows
  const int lane = threadIdx.x & 63;
  const float4 dv = *(const float4*)(D + (size_t)r * NN + lane * 4);
  double d0 = dv.x, d1 = dv.y, d2 = dv.z, d3 = dv.w;
  double p0 = d0, p1 = p0 + d1, p2 = p1 + d2, p3 = p2 + d3;  // local inclusive
  double t = p3;
  #pragma unroll
  for (int d = 1; d < 64; d <<= 1) {
    double u = __shfl_up(t, d);
    if (lane >= d) t += u;
  }
  const double off = t - p3;                 // exclusive prefix of lane totals
  double* srow = S + (size_t)r * NN + lane * 4;
  srow[0] = off + p0; srow[1] = off + p1; srow[2] = off + p2; srow[3] = off + p3;
}

// ---------------- column-wise fp64 scan (in place): 32 blocks x 64 thr ---------
__global__ __launch_bounds__(64) void colscan(double* __restrict__ S)
{
  const int b  = blockIdx.x >> 2;
  const int j  = (blockIdx.x & 3) * 64 + threadIdx.x;
  double* p = S + (size_t)b * NN * NN + j;
  double sum = 0.0;
  for (int r = 0; r < NN; r += 8) {
    double v0 = p[(size_t)(r+0)*NN], v1 = p[(size_t)(r+1)*NN];
    double v2 = p[(size_t)(r+2)*NN], v3 = p[(size_t)(r+3)*NN];
    double v4 = p[(size_t)(r+4)*NN], v5 = p[(size_t)(r+5)*NN];
    double v6 = p[(size_t)(r+6)*NN], v7 = p[(size_t)(r+7)*NN];
    v0 += sum; v1 += v0; v2 += v1; v3 += v2; v4 += v3; v5 += v4; v6 += v5; v7 += v6;
    p[(size_t)(r+0)*NN] = v0; p[(size_t)(r+1)*NN] = v1;
    p[(size_t)(r+2)*NN] = v2; p[(size_t)(r+3)*NN] = v3;
    p[(size_t)(r+4)*NN] = v4; p[(size_t)(r+5)*NN] = v5;
    p[(size_t)(r+6)*NN] = v6; p[(size_t)(r+7)*NN] = v7;
    sum = v7;
  }
}

// ---------------- Ds -> A (shifted), C0 -> Cstk[0], out init -------------------
// Ds[n,j] (j>=n) = S[j][j] - 2*S[n-1][j] + S[n-1][n-1];  A[n][j+1] = Ds[n][j]
// A[n][0] = INF;  Cstk[0][n] = Ds[n][N-1];  out[b][j] = (j==N-1)
__global__ __launch_bounds__(1024) void ds_mat(
    const double* __restrict__ S, float* __restrict__ A,
    float* __restrict__ Cstk, float* __restrict__ out)
{
  const int b = blockIdx.x;
  const double* Sb = S + (size_t)b * NN * NN;
  float* Ab = A + (size_t)b * NN * NN;
  const int tid = threadIdx.x;
  const int w = tid >> 6, lane = tid & 63;
  __shared__ double diag[NN];
  __shared__ float c0sh[NN];
  if (tid < NN) diag[tid] = Sb[(size_t)tid * NN + tid];
  __syncthreads();
  for (int t = 0; t < 16; t++) {
    const int n = w * 16 + t;
    const double snn = (n > 0) ? diag[n-1] : 0.0;
    const double* srow = Sb + (size_t)(n > 0 ? n-1 : 0) * NN;
    #pragma unroll
    for (int c = 0; c < 4; c++) {
      const int j = c * 64 + lane;
      float ds = INF;
      if (j >= n) {
        const double sv = (n > 0) ? srow[j] : 0.0;
        ds = (float)(diag[j] - 2.0 * sv + snn);
      }
      if (j < NN - 1) Ab[(size_t)n * NN + j + 1] = ds;
      else            c0sh[n] = ds;              // Ds[n][N-1]
      if (j == 0)     Ab[(size_t)n * NN + 0] = INF;
    }
  }
  __syncthreads();
  if (tid < NN) {
    Cstk[(size_t)b * 32 * NN + tid] = c0sh[tid];
    out[b * NN + tid] = (tid == NN - 1) ? 1.0f : 0.0f;
  }
}

// ---------------- min-plus MM: C = P (x) Q, 64x64 tile, per batch --------------
// P, Q strictly upper triangular (INF below): skip lower tiles + clamp k range.
__global__ __launch_bounds__(256) void mp_mm(
    const float* __restrict__ P, const float* __restrict__ Q, float* __restrict__ Cm)
{
  const int b = blockIdx.z;
  const int tid = threadIdx.x;
  const int tx = tid & 15;
  const int ty = tid >> 4;
  const int rowBase = blockIdx.y * 64;
  const int colBase = blockIdx.x * 64;
  float* Cb = Cm + (size_t)b * NN * NN;
  if (colBase < rowBase) {             // strictly-lower tile: all INF
    #pragma unroll
    for (int i = 0; i < 4; i++)
      #pragma unroll
      for (int j = 0; j < 4; j++)
        Cb[(size_t)(rowBase + ty*4 + i) * NN + (colBase + tx*4 + j)] = INF;
    return;
  }
  const float* Pb = P + (size_t)b * NN * NN;
  const float* Qb = Q + (size_t)b * NN * NN;
  __shared__ float As[16][64];
  __shared__ float Bs[16][64];
  float acc[4][4];
  #pragma unroll
  for (int i = 0; i < 4; i++)
    #pragma unroll
    for (int j = 0; j < 4; j++) acc[i][j] = INF;
  const int kHi = (colBase + 64 < NN) ? colBase + 64 : NN;
  for (int k0 = rowBase; k0 < kHi; k0 += 16) {
    {
      const int r  = tid >> 2;
      const int kq = (tid & 3) << 2;
      const float4 av = *(const float4*)(Pb + (size_t)(rowBase + r) * NN + (k0 + kq));
      As[kq+0][r] = av.x; As[kq+1][r] = av.y; As[kq+2][r] = av.z; As[kq+3][r] = av.w;
      const int kr = tid >> 4;
      const int c4 = (tid & 15) << 2;
      const float4 bv = *(const float4*)(Qb + (size_t)(k0 + kr) * NN + (colBase + c4));
      Bs[kr][c4+0] = bv.x; Bs[kr][c4+1] = bv.y; Bs[kr][c4+2] = bv.z; Bs[kr][c4+3] = bv.w;
    }
    __syncthreads();
    #pragma unroll
    for (int kk = 0; kk < 16; kk++) {
      const float4 a = *(const float4*)&As[kk][ty*4];
      const float4 bq = *(const float4*)&Bs[kk][tx*4];
      const float ar[4] = {a.x, a.y, a.z, a.w};
      const float br[4] = {bq.x, bq.y, bq.z, bq.w};
      #pragma unroll
      for (int i = 0; i < 4; i++)
        #pragma unroll
        for (int j = 0; j < 4; j++)
          acc[i][j] = fminf(acc[i][j], ar[i] + br[j]);
    }
    __syncthreads();
  }
  #pragma unroll
  for (int i = 0; i < 4; i++)
    #pragma unroll
    for (int j = 0; j < 4; j++)
      Cb[(size_t)(rowBase + ty*4 + i) * NN + (colBase + tx*4 + j)] =
          fminf(acc[i][j], INF);
}

// ---------------- full chain C_1..C_29 in one kernel: 1 block/batch ------------
// A4's finite part is strictly upper-triangular (jj >= n+4): packed at float4
// granularity it is 32256 floats (126 KB) and fits in LDS. The 7 A4 stages then
// run entirely from LDS instead of re-reading 160 KB from L2 per stage behind a
// barrier (latency-bound: VALUBusy ~39% on active CUs). C vectors live in an
// 8-slot ring (stage t reads slots (4t..4t+3)&7, writes (4t+4..4t+7)&7).
constexpr int CSTR = 260;    // LDS stride: 16B-aligned, breaks pow2 banks
constexpr int RING = 8;      // ring depth (power of 2)
constexpr int A4F  = 32256;  // packed upper-tri A4 float count

template<int W>
__device__ __forceinline__ void mp_stage_g(
    const float* __restrict__ P, size_t mb, int n, int q,
    const float* cs, int kin, float* outm)
{
  const float* Pr = P + mb + (size_t)n * NN + q * 64;
  float m[W];
  #pragma unroll
  for (int v = 0; v < W; v++) m[v] = INF;
  if (q * 64 + 63 > n) {          // chunk contains some j > n (else all INF)
    #pragma unroll 4
    for (int i = 0; i < 16; i++) {
      const float4 a = *(const float4*)(Pr + i * 4);
      #pragma unroll
      for (int v = 0; v < W; v++) {
        const float4 c = *(const float4*)&cs[((kin + v) & (RING-1)) * CSTR + q * 64 + i * 4];
        m[v] = fminf(m[v], fminf(fminf(a.x + c.x, a.y + c.y),
                                 fminf(a.z + c.z, a.w + c.w)));
      }
    }
  }
  #pragma unroll
  for (int v = 0; v < W; v++) {
    m[v] = fminf(m[v], __shfl_xor(m[v], 1));
    m[v] = fminf(m[v], __shfl_xor(m[v], 2));
    outm[v] = fminf(m[v], INF);
  }
}

__global__ __launch_bounds__(1024) void chain_full(
    const float* __restrict__ A, const float* __restrict__ A2,
    const float* __restrict__ A4, float* __restrict__ Cstk)
{
  const int b = blockIdx.x;
  const int tid = threadIdx.x;
  const int n = tid >> 2, q = tid & 3;
  __shared__ __align__(16) float cs[RING * CSTR];    //   8.3 KB
  __shared__ __align__(16) float a4s[A4F];           // 126.0 KB
  float* Ck = Cstk + (size_t)b * 32 * NN;
  const size_t mb = (size_t)b * NN * NN;

  // packed-A4 row geometry for this thread's row n:
  //   row n stores cols [(n+4)&~3, 256) at offset rowOff[n] (closed form)
  const int g = n >> 2, r4 = n & 3;
  const int rowOff = 256 * n - 8 * g * (g + 1) - 4 * r4 * (g + 1);
  const int jjA = (n + 4) & ~3;

  // ---- stage packed A4 into LDS (4 threads per row, stride-4 over float4s) ----
  {
    const int nf4row = (256 - jjA) >> 2;             // 0 for rows 252..255
    const float* src = A4 + mb + (size_t)n * NN + jjA;
    float* dst = a4s + rowOff;
    #pragma unroll 4
    for (int i = q; i < nf4row; i += 4)
      *(float4*)(dst + 4 * i) = *(const float4*)(src + 4 * i);
  }
  if (tid < NN) cs[tid] = Ck[tid];                   // ring slot 0 = C0
  __syncthreads();

  float m1[1];
  mp_stage_g<1>(A, mb, n, q, cs, 0, m1);
  if (q == 0) { cs[1 * CSTR + n] = m1[0]; Ck[1 * NN + n] = m1[0]; }
  __syncthreads();

  float m2[2];
  mp_stage_g<2>(A2, mb, n, q, cs, 0, m2);
  if (q == 0) {
    cs[2 * CSTR + n] = m2[0]; Ck[2 * NN + n] = m2[0];
    cs[3 * CSTR + n] = m2[1]; Ck[3 * NN + n] = m2[1];
  }
  __syncthreads();

  // per-thread packed segment of chunk q: jj in [jstart, 64q+64), all >= jjA
  const int jstart = (64 * q > jjA) ? 64 * q : jjA;
  const int nf4 = (64 * q + 64 - jstart) >> 2;       // <= 0: all-INF segment
  const float* ap = a4s + rowOff + (jstart - jjA);

  for (int t = 0; t < 7; t++) {
    float m4[4];
    #pragma unroll
    for (int v = 0; v < 4; v++) m4[v] = INF;
    #pragma unroll 2
    for (int i = 0; i < nf4; i++) {
      const float4 a = *(const float4*)(ap + 4 * i);
      #pragma unroll
      for (int v = 0; v < 4; v++) {
        const float4 c = *(const float4*)&cs[((4 * t + v) & (RING-1)) * CSTR + jstart + 4 * i];
        m4[v] = fminf(m4[v], fminf(fminf(a.x + c.x, a.y + c.y),
                                   fminf(a.z + c.z, a.w + c.w)));
      }
    }
    #pragma unroll
    for (int v = 0; v < 4; v++) {
      m4[v] = fminf(m4[v], __shfl_xor(m4[v], 1));
      m4[v] = fminf(m4[v], __shfl_xor(m4[v], 2));
      m4[v] = fminf(m4[v], INF);
    }
    if (q == 0) {
      #pragma unroll
      for (int v = 0; v < 4; v++) {
        const int k = 4 * t + 4 + v;
        cs[(k & (RING-1)) * CSTR + n] = m4[v];
        Ck[k * NN + n] = m4[v];
      }
    }
    __syncthreads();
  }
}

// ---------------- softmax pass 1: row sums (coalesced float4) ------------------
// s_n = sum_{jj=n+1}^{limit} exp(C_k[n] - A[n][jj] - C_{k-1}[jj]); invs = 1/s
// (jj <= n terms auto-zero via A INF; only jj <= limit mask is explicit)
__global__ __launch_bounds__(256) void sm_rows(
    const float* __restrict__ A, const float* __restrict__ Cstk,
    float* __restrict__ invs)
{
  const int rg = blockIdx.x;          // row group 0..3
  const int k  = blockIdx.y + 1;      // 1..29
  const int b  = blockIdx.z;
  const int limit = NN - k;
  const int tid = threadIdx.x;
  const int r = tid >> 2, q = tid & 3;
  const int n = rg * 64 + r;
  __shared__ __align__(16) float cprev[NN];
  __shared__ float ck[NN];
  const float* Ckb = Cstk + (size_t)b * 32 * NN;
  cprev[tid] = Ckb[(k - 1) * NN + tid];
  ck[tid]    = Ckb[k * NN + tid];
  __syncthreads();
  const float m = ck[n];
  const float* Ar = A + (size_t)b * NN * NN + (size_t)n * NN + q * 64;
  float s = 0.f;
  if (q * 64 + 63 > n) {              // chunk has some jj > n
    #pragma unroll 4
    for (int i = 0; i < 16; i++) {
      const float4 a = *(const float4*)(Ar + i * 4);
      const int jj = q * 64 + i * 4;
      const float4 c = *(const float4*)&cprev[jj];
      s += (jj + 0 <= limit) ? __expf(m - a.x - c.x) : 0.f;
      s += (jj + 1 <= limit) ? __expf(m - a.y - c.y) : 0.f;
      s += (jj + 2 <= limit) ? __expf(m - a.z - c.z) : 0.f;
      s += (jj + 3 <= limit) ? __expf(m - a.w - c.w) : 0.f;
    }
  }
  s += __shfl_xor(s, 1);
  s += __shfl_xor(s, 2);
  if (q == 0) invs[((size_t)b * 32 + k) * NN + n] = 1.0f / s;
}

// ---------------- softmax pass 2: column accumulation (coalesced) --------------
__global__ __launch_bounds__(256) void sm_cols(
    const float* __restrict__ A, const float* __restrict__ Cstk,
    const float* __restrict__ invs, float* __restrict__ out)
{
  const int k = blockIdx.x + 1;        // 1..29
  const int b = blockIdx.y;
  const int limit = NN - k;
  const int tid = threadIdx.x;
  const float* Ab = A + (size_t)b * NN * NN;
  const float* Ckb = Cstk + (size_t)b * 32 * NN;
  __shared__ float csh[NN];    // C_{k-1}[j+1]
  __shared__ float mrow[NN];   // C_k[n]
  __shared__ float ivh[NN];
  csh[tid]  = (tid < NN - 1) ? Ckb[(k - 1) * NN + tid + 1] : 0.0f;
  mrow[tid] = Ckb[k * NN + tid];
  ivh[tid]  = invs[((size_t)b * 32 + k) * NN + tid];
  __syncthreads();
  const int j = tid;
  if (j < limit) {
    const float cj = csh[j];
    const int nmax = (j < limit - 1) ? j : limit - 1;
    float a = 0.0f;
    for (int nr = 0; nr <= nmax; nr++)
      a += __expf(mrow[nr] - Ab[(size_t)nr * NN + j + 1] - cj) * ivh[nr];
    int kmaxj = NN - 1 - j; if (kmaxj > KMAX - 1) kmaxj = KMAX - 1;
    const float cnt = (float)((j + 1) * kmaxj);
    atomicAdd(&out[b * NN + j], a / cnt);
  }
}

extern "C" void kernel_launch(void* const* d_in, const int* in_sizes, int n_in,
                              void* d_out, int out_size, void* d_ws, size_t ws_size,
                              hipStream_t stream) {
  const float* x  = (const float*)d_in[0];
  const float* W0 = (const float*)d_in[1];
  const float* b0 = (const float*)d_in[2];
  const float* W1 = (const float*)d_in[3];
  const float* b1 = (const float*)d_in[4];
  float* out = (float*)d_out;

  // ws layout (max 7 MiB + 8 KiB used; ws proven >= 8 MiB + 8 KiB):
  //  region        lifetime
  //  h    [0,2M)   gemm1 W -> gemm2 R
  //  S    [0,4M)   rowscan W (h dead) -> colscan RW -> ds_mat R
  //  A2   [0,2M)   mp_mm1 W (S dead) -> mp_mm2/chain R
  //  A4   [2M,4M)  mp_mm2 W -> chain R
  //  D    [4M,6M)  corr_dist W -> rowscan R
  //  A    [4M,6M)  ds_mat W (D dead) -> mp_mm1/chain/sm R
  //  z    [6M,7M)  gemm2 W -> row_norms/corr_dist R
  //  Cstk [6M,6.25M) ds_mat W (z dead) -> chain RW -> sm R
  //  invs [6.5M,6.75M) sm_rows W -> sm_cols R
  //  norms[7M,+8K) row_norms W -> corr_dist R
  char* base = (char*)d_ws;
  float*  h    = (float*)(base);
  double* S    = (double*)(base);
  float*  A2   = (float*)(base);
  float*  A4   = (float*)(base + (2u << 20));
  float*  D    = (float*)(base + (4u << 20));
  float*  A    = (float*)(base + (4u << 20));
  float*  z    = (float*)(base + (6u << 20));
  float*  Cstk = (float*)(base + (6u << 20));
  float*  invs = (float*)(base + (6u << 20) + (512u << 10));
  float*  norms= (float*)(base + (7u << 20));

  gemm_bias_act<<<dim3(F1/32, ROWS/64), 256, 0, stream>>>(x, W0, b0, h, ROWS, F1, F0, 1);
  gemm_bias_act<<<dim3(F2/32, ROWS/64), 256, 0, stream>>>(h, W1, b1, z, ROWS, F2, F1, 0);
  row_norms<<<dim3(ROWS*64/256), 256, 0, stream>>>(z, norms);
  corr_dist<<<dim3(NN/64, NN/64, NB), 256, 0, stream>>>(z, norms, D);
  rowscan<<<dim3(ROWS/4), 256, 0, stream>>>(D, S);
  colscan<<<dim3(NB*4), 64, 0, stream>>>(S);
  ds_mat<<<dim3(NB), 1024, 0, stream>>>(S, A, Cstk, out);
  mp_mm<<<dim3(NN/64, NN/64, NB), 256, 0, stream>>>(A, A, A2);
  mp_mm<<<dim3(NN/64, NN/64, NB), 256, 0, stream>>>(A2, A2, A4);
  chain_full<<<dim3(NB), 1024, 0, stream>>>(A, A2, A4, Cstk);
  sm_rows<<<dim3(4, KMAX-1, NB), 256, 0, stream>>>(A, Cstk, invs);
  sm_cols<<<dim3(KMAX-1, NB), 256, 0, stream>>>(A, Cstk, invs, out);
}

// Round 2
// 287.423 us; speedup vs baseline: 1.0571x; 1.0531x over previous
//
#include <hip/hip_runtime.h>

constexpr int NB    = 8;     // batches
constexpr int NN    = 256;   // sequence length
constexpr int F0    = 512;
constexpr int F1    = 256;
constexpr int F2    = 128;
constexpr int ROWS  = NB * NN;   // 2048
constexpr int KMAX  = 30;
constexpr float INF = 1e30f;

// ---------------- fp32 GEMM: C = act(A @ B + bias), 64x32 tile, BK=16 ----------
__global__ __launch_bounds__(256) void gemm_bias_act(
    const float* __restrict__ A, const float* __restrict__ B,
    const float* __restrict__ bias, float* __restrict__ C,
    int M, int Ncols, int K, int relu)
{
  __shared__ float As[16][64];   // [k][m]
  __shared__ float Bs[16][32];   // [k][n]
  const int tid = threadIdx.x;
  const int tx = tid & 15;       // col group  (2 cols)
  const int ty = tid >> 4;       // row group  (4 rows)
  const int rowBase = blockIdx.y * 64;
  const int colBase = blockIdx.x * 32;
  float acc[4][2] = {};
  for (int k0 = 0; k0 < K; k0 += 16) {
    {
      const int r  = tid >> 2;
      const int kq = (tid & 3) << 2;
      const float4 av = *(const float4*)(A + (size_t)(rowBase + r) * K + (k0 + kq));
      As[kq+0][r] = av.x; As[kq+1][r] = av.y; As[kq+2][r] = av.z; As[kq+3][r] = av.w;
      const int kr = tid >> 4;
      const int c2 = (tid & 15) << 1;
      const float2 bv = *(const float2*)(B + (size_t)(k0 + kr) * Ncols + (colBase + c2));
      Bs[kr][c2+0] = bv.x; Bs[kr][c2+1] = bv.y;
    }
    __syncthreads();
    #pragma unroll
    for (int kk = 0; kk < 16; kk++) {
      const float4 a = *(const float4*)&As[kk][ty*4];
      const float b0v = Bs[kk][tx*2+0];
      const float b1v = Bs[kk][tx*2+1];
      acc[0][0] += a.x*b0v; acc[0][1] += a.x*b1v;
      acc[1][0] += a.y*b0v; acc[1][1] += a.y*b1v;
      acc[2][0] += a.z*b0v; acc[2][1] += a.z*b1v;
      acc[3][0] += a.w*b0v; acc[3][1] += a.w*b1v;
    }
    __syncthreads();
  }
  #pragma unroll
  for (int i = 0; i < 4; i++) {
    const int rr = rowBase + ty*4 + i;
    #pragma unroll
    for (int j = 0; j < 2; j++) {
      const int cc = colBase + tx*2 + j;
      float v = acc[i][j] + bias[cc];
      if (relu) v = fmaxf(v, 0.0f);
      C[(size_t)rr * Ncols + cc] = v;
    }
  }
}

// ---------------- row norms: norms[r] = ||z_r||^2, one wave per row ------------
__global__ __launch_bounds__(256) void row_norms(
    const float* __restrict__ z, float* __restrict__ norms)
{
  const int wave = (blockIdx.x * blockDim.x + threadIdx.x) >> 6;
  const int lane = threadIdx.x & 63;
  if (wave >= ROWS) return;
  const float* p = z + (size_t)wave * F2;
  float a = p[lane], b = p[lane + 64];
  float v = a*a + b*b;
  #pragma unroll
  for (int d = 32; d; d >>= 1) v += __shfl_xor(v, d);
  if (lane == 0) norms[wave] = v;
}

// ---------------- D[b,n,m] = 0.5*(1 - (z_n.z_m)/sqrt(max(|z_n|^2|z_m|^2,1e-8)))
__global__ __launch_bounds__(256) void corr_dist(
    const float* __restrict__ z, const float* __restrict__ norms,
    float* __restrict__ D)
{
  const int b = blockIdx.z;
  const float* zb = z + (size_t)b * NN * F2;
  __shared__ float As[16][64];  // [k][row]
  __shared__ float Bs[16][64];  // [k][col]
  const int tid = threadIdx.x;
  const int tx = tid & 15;
  const int ty = tid >> 4;
  const int rowBase = blockIdx.y * 64;
  const int colBase = blockIdx.x * 64;
  float acc[4][4] = {};
  for (int k0 = 0; k0 < F2; k0 += 16) {
    {
      const int r  = tid >> 2;
      const int kq = (tid & 3) << 2;
      const float4 av = *(const float4*)(zb + (size_t)(rowBase + r) * F2 + (k0 + kq));
      As[kq+0][r] = av.x; As[kq+1][r] = av.y; As[kq+2][r] = av.z; As[kq+3][r] = av.w;
      const float4 bv = *(const float4*)(zb + (size_t)(colBase + r) * F2 + (k0 + kq));
      Bs[kq+0][r] = bv.x; Bs[kq+1][r] = bv.y; Bs[kq+2][r] = bv.z; Bs[kq+3][r] = bv.w;
    }
    __syncthreads();
    #pragma unroll
    for (int kk = 0; kk < 16; kk++) {
      const float4 a = *(const float4*)&As[kk][ty*4];
      const float4 bq = *(const float4*)&Bs[kk][tx*4];
      const float ar[4] = {a.x, a.y, a.z, a.w};
      const float br[4] = {bq.x, bq.y, bq.z, bq.w};
      #pragma unroll
      for (int i = 0; i < 4; i++)
        #pragma unroll
        for (int j = 0; j < 4; j++)
          acc[i][j] += ar[i] * br[j];
    }
    __syncthreads();
  }
  float* Db = D + (size_t)b * NN * NN;
  #pragma unroll
  for (int i = 0; i < 4; i++) {
    const int rr = rowBase + ty*4 + i;
    const float nr = norms[b*NN + rr];
    #pragma unroll
    for (int j = 0; j < 4; j++) {
      const int cc = colBase + tx*4 + j;
      const float nc = norms[b*NN + cc];
      const float denom = sqrtf(fmaxf(nr * nc, 1e-8f));
      Db[(size_t)rr * NN + cc] = 0.5f * (1.0f - acc[i][j] / denom);
    }
  }
}

// ---------------- row-wise fp64 inclusive scan: one wave per row ----------------
__global__ __launch_bounds__(256) void rowscan(
    const float* __restrict__ D, double* __restrict__ S)
{
  const int r = blockIdx.x * 4 + (threadIdx.x >> 6);   // 2048 rows
  const int lane = threadIdx.x & 63;
  const float4 dv = *(const float4*)(D + (size_t)r * NN + lane * 4);
  double d0 = dv.x, d1 = dv.y, d2 = dv.z, d3 = dv.w;
  double p0 = d0, p1 = p0 + d1, p2 = p1 + d2, p3 = p2 + d3;  // local inclusive
  double t = p3;
  #pragma unroll
  for (int d = 1; d < 64; d <<= 1) {
    double u = __shfl_up(t, d);
    if (lane >= d) t += u;
  }
  const double off = t - p3;                 // exclusive prefix of lane totals
  double* srow = S + (size_t)r * NN + lane * 4;
  srow[0] = off + p0; srow[1] = off + p1; srow[2] = off + p2; srow[3] = off + p3;
}

// ---------------- column-wise fp64 scan (in place): 32 blocks x 64 thr ---------
__global__ __launch_bounds__(64) void colscan(double* __restrict__ S)
{
  const int b  = blockIdx.x >> 2;
  const int j  = (blockIdx.x & 3) * 64 + threadIdx.x;
  double* p = S + (size_t)b * NN * NN + j;
  double sum = 0.0;
  for (int r = 0; r < NN; r += 8) {
    double v0 = p[(size_t)(r+0)*NN], v1 = p[(size_t)(r+1)*NN];
    double v2 = p[(size_t)(r+2)*NN], v3 = p[(size_t)(r+3)*NN];
    double v4 = p[(size_t)(r+4)*NN], v5 = p[(size_t)(r+5)*NN];
    double v6 = p[(size_t)(r+6)*NN], v7 = p[(size_t)(r+7)*NN];
    v0 += sum; v1 += v0; v2 += v1; v3 += v2; v4 += v3; v5 += v4; v6 += v5; v7 += v6;
    p[(size_t)(r+0)*NN] = v0; p[(size_t)(r+1)*NN] = v1;
    p[(size_t)(r+2)*NN] = v2; p[(size_t)(r+3)*NN] = v3;
    p[(size_t)(r+4)*NN] = v4; p[(size_t)(r+5)*NN] = v5;
    p[(size_t)(r+6)*NN] = v6; p[(size_t)(r+7)*NN] = v7;
    sum = v7;
  }
}

// ---------------- Ds -> A (shifted), C0 -> Cstk[0], out init -------------------
// Ds[n,j] (j>=n) = S[j][j] - 2*S[n-1][j] + S[n-1][n-1];  A[n][j+1] = Ds[n][j]
// A[n][0] = INF;  Cstk[0][n] = Ds[n][N-1];  out[b][j] = (j==N-1)
__global__ __launch_bounds__(1024) void ds_mat(
    const double* __restrict__ S, float* __restrict__ A,
    float* __restrict__ Cstk, float* __restrict__ out)
{
  const int b = blockIdx.x;
  const double* Sb = S + (size_t)b * NN * NN;
  float* Ab = A + (size_t)b * NN * NN;
  const int tid = threadIdx.x;
  const int w = tid >> 6, lane = tid & 63;
  __shared__ double diag[NN];
  __shared__ float c0sh[NN];
  if (tid < NN) diag[tid] = Sb[(size_t)tid * NN + tid];
  __syncthreads();
  for (int t = 0; t < 16; t++) {
    const int n = w * 16 + t;
    const double snn = (n > 0) ? diag[n-1] : 0.0;
    const double* srow = Sb + (size_t)(n > 0 ? n-1 : 0) * NN;
    #pragma unroll
    for (int c = 0; c < 4; c++) {
      const int j = c * 64 + lane;
      float ds = INF;
      if (j >= n) {
        const double sv = (n > 0) ? srow[j] : 0.0;
        ds = (float)(diag[j] - 2.0 * sv + snn);
      }
      if (j < NN - 1) Ab[(size_t)n * NN + j + 1] = ds;
      else            c0sh[n] = ds;              // Ds[n][N-1]
      if (j == 0)     Ab[(size_t)n * NN + 0] = INF;
    }
  }
  __syncthreads();
  if (tid < NN) {
    Cstk[(size_t)b * 32 * NN + tid] = c0sh[tid];
    out[b * NN + tid] = (tid == NN - 1) ? 1.0f : 0.0f;
  }
}

// ---------------- min-plus MM: C = P (x) Q, 64x64 tile, per batch --------------
// P, Q strictly upper triangular (INF below): skip lower tiles + clamp k range.
__global__ __launch_bounds__(256) void mp_mm(
    const float* __restrict__ P, const float* __restrict__ Q, float* __restrict__ Cm)
{
  const int b = blockIdx.z;
  const int tid = threadIdx.x;
  const int tx = tid & 15;
  const int ty = tid >> 4;
  const int rowBase = blockIdx.y * 64;
  const int colBase = blockIdx.x * 64;
  float* Cb = Cm + (size_t)b * NN * NN;
  if (colBase < rowBase) {             // strictly-lower tile: all INF
    #pragma unroll
    for (int i = 0; i < 4; i++)
      #pragma unroll
      for (int j = 0; j < 4; j++)
        Cb[(size_t)(rowBase + ty*4 + i) * NN + (colBase + tx*4 + j)] = INF;
    return;
  }
  const float* Pb = P + (size_t)b * NN * NN;
  const float* Qb = Q + (size_t)b * NN * NN;
  __shared__ float As[16][64];
  __shared__ float Bs[16][64];
  float acc[4][4];
  #pragma unroll
  for (int i = 0; i < 4; i++)
    #pragma unroll
    for (int j = 0; j < 4; j++) acc[i][j] = INF;
  const int kHi = (colBase + 64 < NN) ? colBase + 64 : NN;
  for (int k0 = rowBase; k0 < kHi; k0 += 16) {
    {
      const int r  = tid >> 2;
      const int kq = (tid & 3) << 2;
      const float4 av = *(const float4*)(Pb + (size_t)(rowBase + r) * NN + (k0 + kq));
      As[kq+0][r] = av.x; As[kq+1][r] = av.y; As[kq+2][r] = av.z; As[kq+3][r] = av.w;
      const int kr = tid >> 4;
      const int c4 = (tid & 15) << 2;
      const float4 bv = *(const float4*)(Qb + (size_t)(k0 + kr) * NN + (colBase + c4));
      Bs[kr][c4+0] = bv.x; Bs[kr][c4+1] = bv.y; Bs[kr][c4+2] = bv.z; Bs[kr][c4+3] = bv.w;
    }
    __syncthreads();
    #pragma unroll
    for (int kk = 0; kk < 16; kk++) {
      const float4 a = *(const float4*)&As[kk][ty*4];
      const float4 bq = *(const float4*)&Bs[kk][tx*4];
      const float ar[4] = {a.x, a.y, a.z, a.w};
      const float br[4] = {bq.x, bq.y, bq.z, bq.w};
      #pragma unroll
      for (int i = 0; i < 4; i++)
        #pragma unroll
        for (int j = 0; j < 4; j++)
          acc[i][j] = fminf(acc[i][j], ar[i] + br[j]);
    }
    __syncthreads();
  }
  #pragma unroll
  for (int i = 0; i < 4; i++)
    #pragma unroll
    for (int j = 0; j < 4; j++)
      Cb[(size_t)(rowBase + ty*4 + i) * NN + (colBase + tx*4 + j)] =
          fminf(acc[i][j], INF);
}

// ---------------- full chain C_1..C_29 in one kernel: 1 block/batch ------------
// A4's finite part (jj >= n+4) lives in LDS, packed by ROW-GROUP a = n>>2:
// group a stores jj in [4a+4,256) for each of its 4 rows (same stored set as
// float4-granular packing), row stride STR ≡ 16 (mod 32 banks). A wave's 16
// rows = 4 groups; each group's 4 rows tile all 32 banks 2-deep, 4 groups ->
// exactly 8-deep = the 1024B/clk LDS floor: zero excess bank conflict.
// Threads q=0..3 of a row interleave jj by 16 floats (f = 4q; f += 16), so the
// 4 q-lanes read 64 consecutive bytes (the old 64-float chunks put all q on
// the same bank group: 64 ≡ 0 mod 32 -> measured 308K conflict-cycles).
// C vectors live in an 8-slot ring (stage t reads (4t..4t+3)&7, writes +4..+7).
constexpr int CSTR   = 260;    // ring stride: 16B-aligned, breaks pow2 banks
constexpr int RING   = 8;      // ring depth (power of 2)
constexpr int A4PADF = 35776;  // group-padded packed A4 float count

template<int W>
__device__ __forceinline__ void mp_stage_g(
    const float* __restrict__ P, size_t mb, int n, int q,
    const float* cs, int kin, float* outm)
{
  const float* Pr = P + mb + (size_t)n * NN + q * 64;
  float m[W];
  #pragma unroll
  for (int v = 0; v < W; v++) m[v] = INF;
  if (q * 64 + 63 > n) {          // chunk contains some j > n (else all INF)
    #pragma unroll 4
    for (int i = 0; i < 16; i++) {
      const float4 a = *(const float4*)(Pr + i * 4);
      #pragma unroll
      for (int v = 0; v < W; v++) {
        const float4 c = *(const float4*)&cs[((kin + v) & (RING-1)) * CSTR + q * 64 + i * 4];
        m[v] = fminf(m[v], fminf(fminf(a.x + c.x, a.y + c.y),
                                 fminf(a.z + c.z, a.w + c.w)));
      }
    }
  }
  #pragma unroll
  for (int v = 0; v < W; v++) {
    m[v] = fminf(m[v], __shfl_xor(m[v], 1));
    m[v] = fminf(m[v], __shfl_xor(m[v], 2));
    outm[v] = fminf(m[v], INF);
  }
}

__global__ __launch_bounds__(1024) void chain_full(
    const float* __restrict__ A, const float* __restrict__ A2,
    const float* __restrict__ A4, float* __restrict__ Cstk)
{
  const int b = blockIdx.x;
  const int tid = threadIdx.x;
  const int n = tid >> 2, q = tid & 3;
  __shared__ __align__(16) float cs[RING * CSTR];    //   8.3 KB
  __shared__ __align__(16) float a4s[A4PADF];        // 139.8 KB
  float* Ck = Cstk + (size_t)b * 32 * NN;
  const size_t mb = (size_t)b * NN * NN;

  // ---- conflict-free packed-A4 geometry (closed form, verified a=0,1,2,8,62,63)
  const int ga = n >> 2, gr = n & 3;
  const int La = 252 - 4 * ga;                  // stored floats/row (0: ga=63)
  const int pad = (4 * ga + 20) & 31;           // -> stride ≡ 16 (mod 32)
  const int STR = La + pad;
  const int t8 = ga & 7;                        // pad prefix within 8-cycle
  const int PP = (t8 < 4) ? (2 * t8 * t8 + 18 * t8)
                          : (72 + 2 * (t8 - 4) * (t8 - 5) + 4 * (t8 - 4));
  const int Bg = 4 * (252 * ga - 2 * ga * (ga - 1) + 112 * (ga >> 3) + PP);
  const int rowA = Bg + gr * STR;               // this row's base float index
  const int jj0 = 4 * ga + 4;                   // first stored jj

  // ---- stage packed A4 into LDS (q-lanes interleave 16B within the row) ----
  {
    const float* src = A4 + mb + (size_t)n * NN + jj0;
    #pragma unroll 4
    for (int f = 4 * q; f < La; f += 16)
      *(float4*)(a4s + rowA + f) = *(const float4*)(src + f);
  }
  if (tid < NN) cs[tid] = Ck[tid];              // ring slot 0 = C0
  __syncthreads();

  float m1[1];
  mp_stage_g<1>(A, mb, n, q, cs, 0, m1);
  if (q == 0) { cs[1 * CSTR + n] = m1[0]; Ck[1 * NN + n] = m1[0]; }
  __syncthreads();

  float m2[2];
  mp_stage_g<2>(A2, mb, n, q, cs, 0, m2);
  if (q == 0) {
    cs[2 * CSTR + n] = m2[0]; Ck[2 * NN + n] = m2[0];
    cs[3 * CSTR + n] = m2[1]; Ck[3 * NN + n] = m2[1];
  }
  __syncthreads();

  const float* ap = a4s + rowA;
  for (int t = 0; t < 7; t++) {
    float m4[4];
    #pragma unroll
    for (int v = 0; v < 4; v++) m4[v] = INF;
    #pragma unroll 4
    for (int f = 4 * q; f < La; f += 16) {
      const float4 a = *(const float4*)(ap + f);
      const int jj = jj0 + f;
      #pragma unroll
      for (int v = 0; v < 4; v++) {
        const float4 c = *(const float4*)&cs[((4 * t + v) & (RING-1)) * CSTR + jj];
        m4[v] = fminf(m4[v], fminf(fminf(a.x + c.x, a.y + c.y),
                                   fminf(a.z + c.z, a.w + c.w)));
      }
    }
    #pragma unroll
    for (int v = 0; v < 4; v++) {
      m4[v] = fminf(m4[v], __shfl_xor(m4[v], 1));
      m4[v] = fminf(m4[v], __shfl_xor(m4[v], 2));
      m4[v] = fminf(m4[v], INF);
    }
    if (q == 0) {
      #pragma unroll
      for (int v = 0; v < 4; v++) {
        const int k = 4 * t + 4 + v;
        cs[(k & (RING-1)) * CSTR + n] = m4[v];
        Ck[k * NN + n] = m4[v];
      }
    }
    __syncthreads();
  }
}

// ---------------- softmax pass 1: row sums (coalesced float4) ------------------
// s_n = sum_{jj=n+1}^{limit} exp(C_k[n] - A[n][jj] - C_{k-1}[jj]); invs = 1/s
// (jj <= n terms auto-zero via A INF; only jj <= limit mask is explicit)
__global__ __launch_bounds__(256) void sm_rows(
    const float* __restrict__ A, const float* __restrict__ Cstk,
    float* __restrict__ invs)
{
  const int rg = blockIdx.x;          // row group 0..3
  const int k  = blockIdx.y + 1;      // 1..29
  const int b  = blockIdx.z;
  const int limit = NN - k;
  const int tid = threadIdx.x;
  const int r = tid >> 2, q = tid & 3;
  const int n = rg * 64 + r;
  __shared__ __align__(16) float cprev[NN];
  __shared__ float ck[NN];
  const float* Ckb = Cstk + (size_t)b * 32 * NN;
  cprev[tid] = Ckb[(k - 1) * NN + tid];
  ck[tid]    = Ckb[k * NN + tid];
  __syncthreads();
  const float m = ck[n];
  const float* Ar = A + (size_t)b * NN * NN + (size_t)n * NN + q * 64;
  float s = 0.f;
  if (q * 64 + 63 > n) {              // chunk has some jj > n
    #pragma unroll 4
    for (int i = 0; i < 16; i++) {
      const float4 a = *(const float4*)(Ar + i * 4);
      const int jj = q * 64 + i * 4;
      const float4 c = *(const float4*)&cprev[jj];
      s += (jj + 0 <= limit) ? __expf(m - a.x - c.x) : 0.f;
      s += (jj + 1 <= limit) ? __expf(m - a.y - c.y) : 0.f;
      s += (jj + 2 <= limit) ? __expf(m - a.z - c.z) : 0.f;
      s += (jj + 3 <= limit) ? __expf(m - a.w - c.w) : 0.f;
    }
  }
  s += __shfl_xor(s, 1);
  s += __shfl_xor(s, 2);
  if (q == 0) invs[((size_t)b * 32 + k) * NN + n] = 1.0f / s;
}

// ---------------- softmax pass 2: column accumulation (coalesced) --------------
__global__ __launch_bounds__(256) void sm_cols(
    const float* __restrict__ A, const float* __restrict__ Cstk,
    const float* __restrict__ invs, float* __restrict__ out)
{
  const int k = blockIdx.x + 1;        // 1..29
  const int b = blockIdx.y;
  const int limit = NN - k;
  const int tid = threadIdx.x;
  const float* Ab = A + (size_t)b * NN * NN;
  const float* Ckb = Cstk + (size_t)b * 32 * NN;
  __shared__ float csh[NN];    // C_{k-1}[j+1]
  __shared__ float mrow[NN];   // C_k[n]
  __shared__ float ivh[NN];
  csh[tid]  = (tid < NN - 1) ? Ckb[(k - 1) * NN + tid + 1] : 0.0f;
  mrow[tid] = Ckb[k * NN + tid];
  ivh[tid]  = invs[((size_t)b * 32 + k) * NN + tid];
  __syncthreads();
  const int j = tid;
  if (j < limit) {
    const float cj = csh[j];
    const int nmax = (j < limit - 1) ? j : limit - 1;
    float a = 0.0f;
    for (int nr = 0; nr <= nmax; nr++)
      a += __expf(mrow[nr] - Ab[(size_t)nr * NN + j + 1] - cj) * ivh[nr];
    int kmaxj = NN - 1 - j; if (kmaxj > KMAX - 1) kmaxj = KMAX - 1;
    const float cnt = (float)((j + 1) * kmaxj);
    atomicAdd(&out[b * NN + j], a / cnt);
  }
}

extern "C" void kernel_launch(void* const* d_in, const int* in_sizes, int n_in,
                              void* d_out, int out_size, void* d_ws, size_t ws_size,
                              hipStream_t stream) {
  const float* x  = (const float*)d_in[0];
  const float* W0 = (const float*)d_in[1];
  const float* b0 = (const float*)d_in[2];
  const float* W1 = (const float*)d_in[3];
  const float* b1 = (const float*)d_in[4];
  float* out = (float*)d_out;

  // ws layout (max 7 MiB + 8 KiB used; ws proven >= 8 MiB + 8 KiB):
  //  region        lifetime
  //  h    [0,2M)   gemm1 W -> gemm2 R
  //  S    [0,4M)   rowscan W (h dead) -> colscan RW -> ds_mat R
  //  A2   [0,2M)   mp_mm1 W (S dead) -> mp_mm2/chain R
  //  A4   [2M,4M)  mp_mm2 W -> chain R
  //  D    [4M,6M)  corr_dist W -> rowscan R
  //  A    [4M,6M)  ds_mat W (D dead) -> mp_mm1/chain/sm R
  //  z    [6M,7M)  gemm2 W -> row_norms/corr_dist R
  //  Cstk [6M,6.25M) ds_mat W (z dead) -> chain RW -> sm R
  //  invs [6.5M,6.75M) sm_rows W -> sm_cols R
  //  norms[7M,+8K) row_norms W -> corr_dist R
  char* base = (char*)d_ws;
  float*  h    = (float*)(base);
  double* S    = (double*)(base);
  float*  A2   = (float*)(base);
  float*  A4   = (float*)(base + (2u << 20));
  float*  D    = (float*)(base + (4u << 20));
  float*  A    = (float*)(base + (4u << 20));
  float*  z    = (float*)(base + (6u << 20));
  float*  Cstk = (float*)(base + (6u << 20));
  float*  invs = (float*)(base + (6u << 20) + (512u << 10));
  float*  norms= (float*)(base + (7u << 20));

  gemm_bias_act<<<dim3(F1/32, ROWS/64), 256, 0, stream>>>(x, W0, b0, h, ROWS, F1, F0, 1);
  gemm_bias_act<<<dim3(F2/32, ROWS/64), 256, 0, stream>>>(h, W1, b1, z, ROWS, F2, F1, 0);
  row_norms<<<dim3(ROWS*64/256), 256, 0, stream>>>(z, norms);
  corr_dist<<<dim3(NN/64, NN/64, NB), 256, 0, stream>>>(z, norms, D);
  rowscan<<<dim3(ROWS/4), 256, 0, stream>>>(D, S);
  colscan<<<dim3(NB*4), 64, 0, stream>>>(S);
  ds_mat<<<dim3(NB), 1024, 0, stream>>>(S, A, Cstk, out);
  mp_mm<<<dim3(NN/64, NN/64, NB), 256, 0, stream>>>(A, A, A2);
  mp_mm<<<dim3(NN/64, NN/64, NB), 256, 0, stream>>>(A2, A2, A4);
  chain_full<<<dim3(NB), 1024, 0, stream>>>(A, A2, A4, Cstk);
  sm_rows<<<dim3(4, KMAX-1, NB), 256, 0, stream>>>(A, Cstk, invs);
  sm_cols<<<dim3(KMAX-1, NB), 256, 0, stream>>>(A, Cstk, invs, out);
}

// Round 3
// 277.004 us; speedup vs baseline: 1.0969x; 1.0376x over previous
//
#include <hip/hip_runtime.h>

constexpr int NB    = 8;     // batches
constexpr int NN    = 256;   // sequence length
constexpr int F0    = 512;
constexpr int F1    = 256;
constexpr int F2    = 128;
constexpr int ROWS  = NB * NN;   // 2048
constexpr int KMAX  = 30;
constexpr float INF = 1e30f;

// ---------------- fp32 GEMM: C = act(A @ B + bias), 64x32 tile, BK=16 ----------
__global__ __launch_bounds__(256) void gemm_bias_act(
    const float* __restrict__ A, const float* __restrict__ B,
    const float* __restrict__ bias, float* __restrict__ C,
    int M, int Ncols, int K, int relu)
{
  __shared__ float As[16][64];   // [k][m]
  __shared__ float Bs[16][32];   // [k][n]
  const int tid = threadIdx.x;
  const int tx = tid & 15;       // col group  (2 cols)
  const int ty = tid >> 4;       // row group  (4 rows)
  const int rowBase = blockIdx.y * 64;
  const int colBase = blockIdx.x * 32;
  float acc[4][2] = {};
  for (int k0 = 0; k0 < K; k0 += 16) {
    {
      const int r  = tid >> 2;
      const int kq = (tid & 3) << 2;
      const float4 av = *(const float4*)(A + (size_t)(rowBase + r) * K + (k0 + kq));
      As[kq+0][r] = av.x; As[kq+1][r] = av.y; As[kq+2][r] = av.z; As[kq+3][r] = av.w;
      const int kr = tid >> 4;
      const int c2 = (tid & 15) << 1;
      const float2 bv = *(const float2*)(B + (size_t)(k0 + kr) * Ncols + (colBase + c2));
      Bs[kr][c2+0] = bv.x; Bs[kr][c2+1] = bv.y;
    }
    __syncthreads();
    #pragma unroll
    for (int kk = 0; kk < 16; kk++) {
      const float4 a = *(const float4*)&As[kk][ty*4];
      const float b0v = Bs[kk][tx*2+0];
      const float b1v = Bs[kk][tx*2+1];
      acc[0][0] += a.x*b0v; acc[0][1] += a.x*b1v;
      acc[1][0] += a.y*b0v; acc[1][1] += a.y*b1v;
      acc[2][0] += a.z*b0v; acc[2][1] += a.z*b1v;
      acc[3][0] += a.w*b0v; acc[3][1] += a.w*b1v;
    }
    __syncthreads();
  }
  #pragma unroll
  for (int i = 0; i < 4; i++) {
    const int rr = rowBase + ty*4 + i;
    #pragma unroll
    for (int j = 0; j < 2; j++) {
      const int cc = colBase + tx*2 + j;
      float v = acc[i][j] + bias[cc];
      if (relu) v = fmaxf(v, 0.0f);
      C[(size_t)rr * Ncols + cc] = v;
    }
  }
}

// ---------------- D[b,n,m] = 0.5*(1 - (z_n.z_m)/sqrt(max(|z_n|^2|z_m|^2,1e-8)))
// Row/col norms accumulated in registers from the same LDS fragments (the old
// row_norms kernel + norms round-trip removed: it was a whole dispatch + gap).
__global__ __launch_bounds__(256) void corr_dist(
    const float* __restrict__ z, float* __restrict__ D)
{
  const int b = blockIdx.z;
  const float* zb = z + (size_t)b * NN * F2;
  __shared__ float As[16][64];  // [k][row]
  __shared__ float Bs[16][64];  // [k][col]
  const int tid = threadIdx.x;
  const int tx = tid & 15;
  const int ty = tid >> 4;
  const int rowBase = blockIdx.y * 64;
  const int colBase = blockIdx.x * 64;
  float acc[4][4] = {};
  float nsr[4] = {}, nsc[4] = {};
  for (int k0 = 0; k0 < F2; k0 += 16) {
    {
      const int r  = tid >> 2;
      const int kq = (tid & 3) << 2;
      const float4 av = *(const float4*)(zb + (size_t)(rowBase + r) * F2 + (k0 + kq));
      As[kq+0][r] = av.x; As[kq+1][r] = av.y; As[kq+2][r] = av.z; As[kq+3][r] = av.w;
      const float4 bv = *(const float4*)(zb + (size_t)(colBase + r) * F2 + (k0 + kq));
      Bs[kq+0][r] = bv.x; Bs[kq+1][r] = bv.y; Bs[kq+2][r] = bv.z; Bs[kq+3][r] = bv.w;
    }
    __syncthreads();
    #pragma unroll
    for (int kk = 0; kk < 16; kk++) {
      const float4 a = *(const float4*)&As[kk][ty*4];
      const float4 bq = *(const float4*)&Bs[kk][tx*4];
      const float ar[4] = {a.x, a.y, a.z, a.w};
      const float br[4] = {bq.x, bq.y, bq.z, bq.w};
      #pragma unroll
      for (int i = 0; i < 4; i++) { nsr[i] += ar[i]*ar[i]; nsc[i] += br[i]*br[i]; }
      #pragma unroll
      for (int i = 0; i < 4; i++)
        #pragma unroll
        for (int j = 0; j < 4; j++)
          acc[i][j] += ar[i] * br[j];
    }
    __syncthreads();
  }
  float* Db = D + (size_t)b * NN * NN;
  #pragma unroll
  for (int i = 0; i < 4; i++) {
    const int rr = rowBase + ty*4 + i;
    #pragma unroll
    for (int j = 0; j < 4; j++) {
      const int cc = colBase + tx*4 + j;
      const float denom = sqrtf(fmaxf(nsr[i] * nsc[j], 1e-8f));
      Db[(size_t)rr * NN + cc] = 0.5f * (1.0f - acc[i][j] / denom);
    }
  }
}

// ---------------- row-wise fp64 inclusive scan: one wave per row ----------------
__global__ __launch_bounds__(256) void rowscan(
    const float* __restrict__ D, double* __restrict__ S)
{
  const int r = blockIdx.x * 4 + (threadIdx.x >> 6);   // 2048 rows
  const int lane = threadIdx.x & 63;
  const float4 dv = *(const float4*)(D + (size_t)r * NN + lane * 4);
  double d0 = dv.x, d1 = dv.y, d2 = dv.z, d3 = dv.w;
  double p0 = d0, p1 = p0 + d1, p2 = p1 + d2, p3 = p2 + d3;  // local inclusive
  double t = p3;
  #pragma unroll
  for (int d = 1; d < 64; d <<= 1) {
    double u = __shfl_up(t, d);
    if (lane >= d) t += u;
  }
  const double off = t - p3;                 // exclusive prefix of lane totals
  double* srow = S + (size_t)r * NN + lane * 4;
  srow[0] = off + p0; srow[1] = off + p1; srow[2] = off + p2; srow[3] = off + p3;
}

// ---------------- column scan, two-phase (latency fix: 32 waves -> 120 blocks) --
// Phase 1: each block scans a 32-row slab of one batch's columns, stores slab
// totals to aux. Phase 2: slab s adds sum of totals 0..s-1 to its 32 rows.
// fp64 re-association vs sequential scan: ~1e-16 relative, invisible at 1e-4.
__global__ __launch_bounds__(256) void colscan1(
    double* __restrict__ S, double* __restrict__ aux)
{
  const int b = blockIdx.x >> 3;
  const int s = blockIdx.x & 7;          // 32-row slab
  const int j = threadIdx.x;
  double* p = S + (size_t)b * NN * NN + (size_t)(s * 32) * NN + j;
  double sum = 0.0;
  for (int r = 0; r < 32; r += 8) {
    double v0 = p[(size_t)(r+0)*NN], v1 = p[(size_t)(r+1)*NN];
    double v2 = p[(size_t)(r+2)*NN], v3 = p[(size_t)(r+3)*NN];
    double v4 = p[(size_t)(r+4)*NN], v5 = p[(size_t)(r+5)*NN];
    double v6 = p[(size_t)(r+6)*NN], v7 = p[(size_t)(r+7)*NN];
    v0 += sum; v1 += v0; v2 += v1; v3 += v2; v4 += v3; v5 += v4; v6 += v5; v7 += v6;
    p[(size_t)(r+0)*NN] = v0; p[(size_t)(r+1)*NN] = v1;
    p[(size_t)(r+2)*NN] = v2; p[(size_t)(r+3)*NN] = v3;
    p[(size_t)(r+4)*NN] = v4; p[(size_t)(r+5)*NN] = v5;
    p[(size_t)(r+6)*NN] = v6; p[(size_t)(r+7)*NN] = v7;
    sum = v7;
  }
  aux[((size_t)b * 8 + s) * NN + j] = sum;
}

__global__ __launch_bounds__(256) void colscan2(
    double* __restrict__ S, const double* __restrict__ aux)
{
  const int b = blockIdx.x / 7;
  const int s = 1 + (blockIdx.x % 7);    // slabs 1..7 need offsets
  const int j = threadIdx.x;
  const double* ax = aux + (size_t)b * 8 * NN + j;
  double off = 0.0;
  for (int u = 0; u < s; u++) off += ax[(size_t)u * NN];
  double* p = S + (size_t)b * NN * NN + (size_t)(s * 32) * NN + j;
  #pragma unroll 8
  for (int r = 0; r < 32; r++) p[(size_t)r * NN] += off;
}

// ---------------- Ds -> A (shifted), C0 -> Cstk[0], out init -------------------
// Ds[n,j] (j>=n) = S[j][j] - 2*S[n-1][j] + S[n-1][n-1];  A[n][j+1] = Ds[n][j]
// A[n][0] = INF;  Cstk[0][n] = Ds[n][N-1];  out[b][j] = (j==N-1)
// Widened 8 -> 128 blocks (16 rows each): the old 8-block version ran on 3%
// of the chip, fully latency-bound.
__global__ __launch_bounds__(256) void ds_mat(
    const double* __restrict__ S, float* __restrict__ A,
    float* __restrict__ Cstk, float* __restrict__ out)
{
  const int slab = blockIdx.x;          // 16 rows
  const int b = blockIdx.y;
  const double* Sb = S + (size_t)b * NN * NN;
  float* Ab = A + (size_t)b * NN * NN;
  const int tid = threadIdx.x;
  const int w = tid >> 6, lane = tid & 63;
  __shared__ double diag[NN];
  diag[tid] = Sb[(size_t)tid * NN + tid];
  __syncthreads();
  #pragma unroll
  for (int t = 0; t < 4; t++) {
    const int n = slab * 16 + w * 4 + t;
    const double snn = (n > 0) ? diag[n-1] : 0.0;
    const double* srow = Sb + (size_t)(n > 0 ? n-1 : 0) * NN;
    #pragma unroll
    for (int c = 0; c < 4; c++) {
      const int j = c * 64 + lane;
      float ds = INF;
      if (j >= n) {
        const double sv = (n > 0) ? srow[j] : 0.0;
        ds = (float)(diag[j] - 2.0 * sv + snn);
      }
      if (j < NN - 1) Ab[(size_t)n * NN + j + 1] = ds;
      else            Cstk[(size_t)b * 32 * NN + n] = ds;   // Ds[n][N-1]
      if (j == 0)     Ab[(size_t)n * NN + 0] = INF;
    }
  }
  if (slab == 0) out[b * NN + tid] = (tid == NN - 1) ? 1.0f : 0.0f;
}

// ---------------- min-plus MM: C = P (x) Q, 64x64 tile, per batch --------------
// P, Q strictly upper triangular (INF below): skip lower tiles + clamp k range.
__global__ __launch_bounds__(256) void mp_mm(
    const float* __restrict__ P, const float* __restrict__ Q, float* __restrict__ Cm)
{
  const int b = blockIdx.z;
  const int tid = threadIdx.x;
  const int tx = tid & 15;
  const int ty = tid >> 4;
  const int rowBase = blockIdx.y * 64;
  const int colBase = blockIdx.x * 64;
  float* Cb = Cm + (size_t)b * NN * NN;
  if (colBase < rowBase) {             // strictly-lower tile: all INF
    #pragma unroll
    for (int i = 0; i < 4; i++)
      #pragma unroll
      for (int j = 0; j < 4; j++)
        Cb[(size_t)(rowBase + ty*4 + i) * NN + (colBase + tx*4 + j)] = INF;
    return;
  }
  const float* Pb = P + (size_t)b * NN * NN;
  const float* Qb = Q + (size_t)b * NN * NN;
  __shared__ float As[16][64];
  __shared__ float Bs[16][64];
  float acc[4][4];
  #pragma unroll
  for (int i = 0; i < 4; i++)
    #pragma unroll
    for (int j = 0; j < 4; j++) acc[i][j] = INF;
  const int kHi = (colBase + 64 < NN) ? colBase + 64 : NN;
  for (int k0 = rowBase; k0 < kHi; k0 += 16) {
    {
      const int r  = tid >> 2;
      const int kq = (tid & 3) << 2;
      const float4 av = *(const float4*)(Pb + (size_t)(rowBase + r) * NN + (k0 + kq));
      As[kq+0][r] = av.x; As[kq+1][r] = av.y; As[kq+2][r] = av.z; As[kq+3][r] = av.w;
      const int kr = tid >> 4;
      const int c4 = (tid & 15) << 2;
      const float4 bv = *(const float4*)(Qb + (size_t)(k0 + kr) * NN + (colBase + c4));
      Bs[kr][c4+0] = bv.x; Bs[kr][c4+1] = bv.y; Bs[kr][c4+2] = bv.z; Bs[kr][c4+3] = bv.w;
    }
    __syncthreads();
    #pragma unroll
    for (int kk = 0; kk < 16; kk++) {
      const float4 a = *(const float4*)&As[kk][ty*4];
      const float4 bq = *(const float4*)&Bs[kk][tx*4];
      const float ar[4] = {a.x, a.y, a.z, a.w};
      const float br[4] = {bq.x, bq.y, bq.z, bq.w};
      #pragma unroll
      for (int i = 0; i < 4; i++)
        #pragma unroll
        for (int j = 0; j < 4; j++)
          acc[i][j] = fminf(acc[i][j], ar[i] + br[j]);
    }
    __syncthreads();
  }
  #pragma unroll
  for (int i = 0; i < 4; i++)
    #pragma unroll
    for (int j = 0; j < 4; j++)
      Cb[(size_t)(rowBase + ty*4 + i) * NN + (colBase + tx*4 + j)] =
          fminf(acc[i][j], INF);
}

// ---------------- full chain C_1..C_29 in one kernel: 1 block/batch ------------
// A4's finite part (jj >= n+4) lives in LDS, packed by ROW-GROUP a = n>>2:
// group a stores jj in [4a+4,256) for each of its 4 rows, row stride STR ≡ 16
// (mod 32 banks): a wave's 16 rows tile all 32 banks 8-deep = conflict-free.
// Threads q=0..3 of a row interleave jj by 16 floats (f = 4q; f += 16).
// C vectors live in an 8-slot ring (stage t reads (4t..4t+3)&7, writes +4..+7).
constexpr int CSTR   = 260;    // ring stride: 16B-aligned, breaks pow2 banks
constexpr int RING   = 8;      // ring depth (power of 2)
constexpr int A4PADF = 35776;  // group-padded packed A4 float count

template<int W>
__device__ __forceinline__ void mp_stage_g(
    const float* __restrict__ P, size_t mb, int n, int q,
    const float* cs, int kin, float* outm)
{
  const float* Pr = P + mb + (size_t)n * NN + q * 64;
  float m[W];
  #pragma unroll
  for (int v = 0; v < W; v++) m[v] = INF;
  if (q * 64 + 63 > n) {          // chunk contains some j > n (else all INF)
    #pragma unroll 4
    for (int i = 0; i < 16; i++) {
      const float4 a = *(const float4*)(Pr + i * 4);
      #pragma unroll
      for (int v = 0; v < W; v++) {
        const float4 c = *(const float4*)&cs[((kin + v) & (RING-1)) * CSTR + q * 64 + i * 4];
        m[v] = fminf(m[v], fminf(fminf(a.x + c.x, a.y + c.y),
                                 fminf(a.z + c.z, a.w + c.w)));
      }
    }
  }
  #pragma unroll
  for (int v = 0; v < W; v++) {
    m[v] = fminf(m[v], __shfl_xor(m[v], 1));
    m[v] = fminf(m[v], __shfl_xor(m[v], 2));
    outm[v] = fminf(m[v], INF);
  }
}

__global__ __launch_bounds__(1024) void chain_full(
    const float* __restrict__ A, const float* __restrict__ A2,
    const float* __restrict__ A4, float* __restrict__ Cstk)
{
  const int b = blockIdx.x;
  const int tid = threadIdx.x;
  const int n = tid >> 2, q = tid & 3;
  __shared__ __align__(16) float cs[RING * CSTR];    //   8.3 KB
  __shared__ __align__(16) float a4s[A4PADF];        // 139.8 KB
  float* Ck = Cstk + (size_t)b * 32 * NN;
  const size_t mb = (size_t)b * NN * NN;

  // ---- conflict-free packed-A4 geometry (closed form) ----
  const int ga = n >> 2, gr = n & 3;
  const int La = 252 - 4 * ga;                  // stored floats/row (0: ga=63)
  const int pad = (4 * ga + 20) & 31;           // -> stride ≡ 16 (mod 32)
  const int STR = La + pad;
  const int t8 = ga & 7;                        // pad prefix within 8-cycle
  const int PP = (t8 < 4) ? (2 * t8 * t8 + 18 * t8)
                          : (72 + 2 * (t8 - 4) * (t8 - 5) + 4 * (t8 - 4));
  const int Bg = 4 * (252 * ga - 2 * ga * (ga - 1) + 112 * (ga >> 3) + PP);
  const int rowA = Bg + gr * STR;               // this row's base float index
  const int jj0 = 4 * ga + 4;                   // first stored jj

  // ---- stage packed A4 into LDS (q-lanes interleave 16B within the row) ----
  {
    const float* src = A4 + mb + (size_t)n * NN + jj0;
    #pragma unroll 4
    for (int f = 4 * q; f < La; f += 16)
      *(float4*)(a4s + rowA + f) = *(const float4*)(src + f);
  }
  if (tid < NN) cs[tid] = Ck[tid];              // ring slot 0 = C0
  __syncthreads();

  float m1[1];
  mp_stage_g<1>(A, mb, n, q, cs, 0, m1);
  if (q == 0) { cs[1 * CSTR + n] = m1[0]; Ck[1 * NN + n] = m1[0]; }
  __syncthreads();

  float m2[2];
  mp_stage_g<2>(A2, mb, n, q, cs, 0, m2);
  if (q == 0) {
    cs[2 * CSTR + n] = m2[0]; Ck[2 * NN + n] = m2[0];
    cs[3 * CSTR + n] = m2[1]; Ck[3 * NN + n] = m2[1];
  }
  __syncthreads();

  const float* ap = a4s + rowA;
  for (int t = 0; t < 7; t++) {
    float m4[4];
    #pragma unroll
    for (int v = 0; v < 4; v++) m4[v] = INF;
    #pragma unroll 4
    for (int f = 4 * q; f < La; f += 16) {
      const float4 a = *(const float4*)(ap + f);
      const int jj = jj0 + f;
      #pragma unroll
      for (int v = 0; v < 4; v++) {
        const float4 c = *(const float4*)&cs[((4 * t + v) & (RING-1)) * CSTR + jj];
        m4[v] = fminf(m4[v], fminf(fminf(a.x + c.x, a.y + c.y),
                                   fminf(a.z + c.z, a.w + c.w)));
      }
    }
    #pragma unroll
    for (int v = 0; v < 4; v++) {
      m4[v] = fminf(m4[v], __shfl_xor(m4[v], 1));
      m4[v] = fminf(m4[v], __shfl_xor(m4[v], 2));
      m4[v] = fminf(m4[v], INF);
    }
    if (q == 0) {
      #pragma unroll
      for (int v = 0; v < 4; v++) {
        const int k = 4 * t + 4 + v;
        cs[(k & (RING-1)) * CSTR + n] = m4[v];
        Ck[k * NN + n] = m4[v];
      }
    }
    __syncthreads();
  }
}

// ---------------- softmax pass 1: row sums (coalesced float4) ------------------
// s_n = sum_{jj=n+1}^{limit} exp(C_k[n] - A[n][jj] - C_{k-1}[jj]); invs = 1/s
// (jj <= n terms auto-zero via A INF; only jj <= limit mask is explicit)
__global__ __launch_bounds__(256) void sm_rows(
    const float* __restrict__ A, const float* __restrict__ Cstk,
    float* __restrict__ invs)
{
  const int rg = blockIdx.x;          // row group 0..3
  const int k  = blockIdx.y + 1;      // 1..29
  const int b  = blockIdx.z;
  const int limit = NN - k;
  const int tid = threadIdx.x;
  const int r = tid >> 2, q = tid & 3;
  const int n = rg * 64 + r;
  __shared__ __align__(16) float cprev[NN];
  __shared__ float ck[NN];
  const float* Ckb = Cstk + (size_t)b * 32 * NN;
  cprev[tid] = Ckb[(k - 1) * NN + tid];
  ck[tid]    = Ckb[k * NN + tid];
  __syncthreads();
  const float m = ck[n];
  const float* Ar = A + (size_t)b * NN * NN + (size_t)n * NN + q * 64;
  float s = 0.f;
  if (q * 64 + 63 > n) {              // chunk has some jj > n
    #pragma unroll 4
    for (int i = 0; i < 16; i++) {
      const float4 a = *(const float4*)(Ar + i * 4);
      const int jj = q * 64 + i * 4;
      const float4 c = *(const float4*)&cprev[jj];
      s += (jj + 0 <= limit) ? __expf(m - a.x - c.x) : 0.f;
      s += (jj + 1 <= limit) ? __expf(m - a.y - c.y) : 0.f;
      s += (jj + 2 <= limit) ? __expf(m - a.z - c.z) : 0.f;
      s += (jj + 3 <= limit) ? __expf(m - a.w - c.w) : 0.f;
    }
  }
  s += __shfl_xor(s, 1);
  s += __shfl_xor(s, 2);
  if (q == 0) invs[((size_t)b * 32 + k) * NN + n] = 1.0f / s;
}

// ---------------- softmax pass 2: column accumulation (coalesced) --------------
__global__ __launch_bounds__(256) void sm_cols(
    const float* __restrict__ A, const float* __restrict__ Cstk,
    const float* __restrict__ invs, float* __restrict__ out)
{
  const int k = blockIdx.x + 1;        // 1..29
  const int b = blockIdx.y;
  const int limit = NN - k;
  const int tid = threadIdx.x;
  const float* Ab = A + (size_t)b * NN * NN;
  const float* Ckb = Cstk + (size_t)b * 32 * NN;
  __shared__ float csh[NN];    // C_{k-1}[j+1]
  __shared__ float mrow[NN];   // C_k[n]
  __shared__ float ivh[NN];
  csh[tid]  = (tid < NN - 1) ? Ckb[(k - 1) * NN + tid + 1] : 0.0f;
  mrow[tid] = Ckb[k * NN + tid];
  ivh[tid]  = invs[((size_t)b * 32 + k) * NN + tid];
  __syncthreads();
  const int j = tid;
  if (j < limit) {
    const float cj = csh[j];
    const int nmax = (j < limit - 1) ? j : limit - 1;
    float a = 0.0f;
    #pragma unroll 4
    for (int nr = 0; nr <= nmax; nr++)
      a += __expf(mrow[nr] - Ab[(size_t)nr * NN + j + 1] - cj) * ivh[nr];
    int kmaxj = NN - 1 - j; if (kmaxj > KMAX - 1) kmaxj = KMAX - 1;
    const float cnt = (float)((j + 1) * kmaxj);
    atomicAdd(&out[b * NN + j], a / cnt);
  }
}

extern "C" void kernel_launch(void* const* d_in, const int* in_sizes, int n_in,
                              void* d_out, int out_size, void* d_ws, size_t ws_size,
                              hipStream_t stream) {
  const float* x  = (const float*)d_in[0];
  const float* W0 = (const float*)d_in[1];
  const float* b0 = (const float*)d_in[2];
  const float* W1 = (const float*)d_in[3];
  const float* b1 = (const float*)d_in[4];
  float* out = (float*)d_out;

  // ws layout (max 7 MiB + 128 KiB used; ws proven >= 8 MiB):
  //  region        lifetime
  //  h    [0,2M)   gemm1 W -> gemm2 R
  //  S    [0,4M)   rowscan W (h dead) -> colscan RW -> ds_mat R
  //  A2   [0,2M)   mp_mm1 W (S dead) -> mp_mm2/chain R
  //  A4   [2M,4M)  mp_mm2 W -> chain R
  //  D    [4M,6M)  corr_dist W -> rowscan R
  //  A    [4M,6M)  ds_mat W (D dead) -> mp_mm1/chain/sm R
  //  z    [6M,7M)  gemm2 W -> corr_dist R
  //  Cstk [6M,6.25M) ds_mat W (z dead) -> chain RW -> sm R
  //  invs [6.5M,6.75M) sm_rows W -> sm_cols R
  //  aux  [7M,7M+128K) colscan1 W -> colscan2 R
  char* base = (char*)d_ws;
  float*  h    = (float*)(base);
  double* S    = (double*)(base);
  float*  A2   = (float*)(base);
  float*  A4   = (float*)(base + (2u << 20));
  float*  D    = (float*)(base + (4u << 20));
  float*  A    = (float*)(base + (4u << 20));
  float*  z    = (float*)(base + (6u << 20));
  float*  Cstk = (float*)(base + (6u << 20));
  float*  invs = (float*)(base + (6u << 20) + (512u << 10));
  double* aux  = (double*)(base + (7u << 20));

  gemm_bias_act<<<dim3(F1/32, ROWS/64), 256, 0, stream>>>(x, W0, b0, h, ROWS, F1, F0, 1);
  gemm_bias_act<<<dim3(F2/32, ROWS/64), 256, 0, stream>>>(h, W1, b1, z, ROWS, F2, F1, 0);
  corr_dist<<<dim3(NN/64, NN/64, NB), 256, 0, stream>>>(z, D);
  rowscan<<<dim3(ROWS/4), 256, 0, stream>>>(D, S);
  colscan1<<<dim3(NB*8), 256, 0, stream>>>(S, aux);
  colscan2<<<dim3(NB*7), 256, 0, stream>>>(S, aux);
  ds_mat<<<dim3(16, NB), 256, 0, stream>>>(S, A, Cstk, out);
  mp_mm<<<dim3(NN/64, NN/64, NB), 256, 0, stream>>>(A, A, A2);
  mp_mm<<<dim3(NN/64, NN/64, NB), 256, 0, stream>>>(A2, A2, A4);
  chain_full<<<dim3(NB), 1024, 0, stream>>>(A, A2, A4, Cstk);
  sm_rows<<<dim3(4, KMAX-1, NB), 256, 0, stream>>>(A, Cstk, invs);
  sm_cols<<<dim3(KMAX-1, NB), 256, 0, stream>>>(A, Cstk, invs, out);
}

// Round 4
// 248.652 us; speedup vs baseline: 1.2219x; 1.1140x over previous
//
#include <hip/hip_runtime.h>

constexpr int NB    = 8;     // batches
constexpr int NN    = 256;   // sequence length
constexpr int F0    = 512;
constexpr int F1    = 256;
constexpr int F2    = 128;
constexpr int ROWS  = NB * NN;   // 2048
constexpr int KMAX  = 30;
constexpr float INF = 1e30f;

// ---------------- fp32 GEMM: C = act(A @ B + bias), 64x32 tile, BK=16 ----------
__global__ __launch_bounds__(256) void gemm_bias_act(
    const float* __restrict__ A, const float* __restrict__ B,
    const float* __restrict__ bias, float* __restrict__ C,
    int M, int Ncols, int K, int relu)
{
  __shared__ float As[16][64];   // [k][m]
  __shared__ float Bs[16][32];   // [k][n]
  const int tid = threadIdx.x;
  const int tx = tid & 15;       // col group  (2 cols)
  const int ty = tid >> 4;       // row group  (4 rows)
  const int rowBase = blockIdx.y * 64;
  const int colBase = blockIdx.x * 32;
  float acc[4][2] = {};
  for (int k0 = 0; k0 < K; k0 += 16) {
    {
      const int r  = tid >> 2;
      const int kq = (tid & 3) << 2;
      const float4 av = *(const float4*)(A + (size_t)(rowBase + r) * K + (k0 + kq));
      As[kq+0][r] = av.x; As[kq+1][r] = av.y; As[kq+2][r] = av.z; As[kq+3][r] = av.w;
      const int kr = tid >> 4;
      const int c2 = (tid & 15) << 1;
      const float2 bv = *(const float2*)(B + (size_t)(k0 + kr) * Ncols + (colBase + c2));
      Bs[kr][c2+0] = bv.x; Bs[kr][c2+1] = bv.y;
    }
    __syncthreads();
    #pragma unroll
    for (int kk = 0; kk < 16; kk++) {
      const float4 a = *(const float4*)&As[kk][ty*4];
      const float b0v = Bs[kk][tx*2+0];
      const float b1v = Bs[kk][tx*2+1];
      acc[0][0] += a.x*b0v; acc[0][1] += a.x*b1v;
      acc[1][0] += a.y*b0v; acc[1][1] += a.y*b1v;
      acc[2][0] += a.z*b0v; acc[2][1] += a.z*b1v;
      acc[3][0] += a.w*b0v; acc[3][1] += a.w*b1v;
    }
    __syncthreads();
  }
  #pragma unroll
  for (int i = 0; i < 4; i++) {
    const int rr = rowBase + ty*4 + i;
    #pragma unroll
    for (int j = 0; j < 2; j++) {
      const int cc = colBase + tx*2 + j;
      float v = acc[i][j] + bias[cc];
      if (relu) v = fmaxf(v, 0.0f);
      C[(size_t)rr * Ncols + cc] = v;
    }
  }
}

// ---------------- D[b,n,m] = 0.5*(1 - (z_n.z_m)/sqrt(max(|z_n|^2|z_m|^2,1e-8)))
// Row/col norms accumulated in registers from the same LDS fragments.
__global__ __launch_bounds__(256) void corr_dist(
    const float* __restrict__ z, float* __restrict__ D)
{
  const int b = blockIdx.z;
  const float* zb = z + (size_t)b * NN * F2;
  __shared__ float As[16][64];  // [k][row]
  __shared__ float Bs[16][64];  // [k][col]
  const int tid = threadIdx.x;
  const int tx = tid & 15;
  const int ty = tid >> 4;
  const int rowBase = blockIdx.y * 64;
  const int colBase = blockIdx.x * 64;
  float acc[4][4] = {};
  float nsr[4] = {}, nsc[4] = {};
  for (int k0 = 0; k0 < F2; k0 += 16) {
    {
      const int r  = tid >> 2;
      const int kq = (tid & 3) << 2;
      const float4 av = *(const float4*)(zb + (size_t)(rowBase + r) * F2 + (k0 + kq));
      As[kq+0][r] = av.x; As[kq+1][r] = av.y; As[kq+2][r] = av.z; As[kq+3][r] = av.w;
      const float4 bv = *(const float4*)(zb + (size_t)(colBase + r) * F2 + (k0 + kq));
      Bs[kq+0][r] = bv.x; Bs[kq+1][r] = bv.y; Bs[kq+2][r] = bv.z; Bs[kq+3][r] = bv.w;
    }
    __syncthreads();
    #pragma unroll
    for (int kk = 0; kk < 16; kk++) {
      const float4 a = *(const float4*)&As[kk][ty*4];
      const float4 bq = *(const float4*)&Bs[kk][tx*4];
      const float ar[4] = {a.x, a.y, a.z, a.w};
      const float br[4] = {bq.x, bq.y, bq.z, bq.w};
      #pragma unroll
      for (int i = 0; i < 4; i++) { nsr[i] += ar[i]*ar[i]; nsc[i] += br[i]*br[i]; }
      #pragma unroll
      for (int i = 0; i < 4; i++)
        #pragma unroll
        for (int j = 0; j < 4; j++)
          acc[i][j] += ar[i] * br[j];
    }
    __syncthreads();
  }
  float* Db = D + (size_t)b * NN * NN;
  #pragma unroll
  for (int i = 0; i < 4; i++) {
    const int rr = rowBase + ty*4 + i;
    #pragma unroll
    for (int j = 0; j < 4; j++) {
      const int cc = colBase + tx*4 + j;
      const float denom = sqrtf(fmaxf(nsr[i] * nsc[j], 1e-8f));
      Db[(size_t)rr * NN + cc] = 0.5f * (1.0f - acc[i][j] / denom);
    }
  }
}

// ---------------- fused row scan + slab column scan (was rowscan + colscan1) ---
// Block = (batch, 32-row slab): row-scan 32 rows into a 64 KB LDS slab
// (wave w does rows w*8..w*8+7), then column-scan the slab in place and emit
// S (slab-local scan) + aux (slab column totals). Cross-slab offsets are
// applied later inside ds_mat (P prefixes) - colscan2 dispatch removed.
__global__ __launch_bounds__(256) void scan_slab(
    const float* __restrict__ D, double* __restrict__ S, double* __restrict__ aux)
{
  const int s = blockIdx.x & 7;
  const int b = blockIdx.x >> 3;
  const int tid = threadIdx.x;
  const int wave = tid >> 6, lane = tid & 63;
  __shared__ double sd[32][NN];    // 64 KB
  for (int t = 0; t < 8; t++) {
    const int rl = wave * 8 + t;
    const float4 dv = *(const float4*)(D + (size_t)(b * NN + s * 32 + rl) * NN + lane * 4);
    double d0 = dv.x, d1 = dv.y, d2 = dv.z, d3 = dv.w;
    double p0 = d0, p1 = p0 + d1, p2 = p1 + d2, p3 = p2 + d3;
    double tt = p3;
    #pragma unroll
    for (int d = 1; d < 64; d <<= 1) {
      double u = __shfl_up(tt, d);
      if (lane >= d) tt += u;
    }
    const double off = tt - p3;
    sd[rl][lane*4+0] = off + p0; sd[rl][lane*4+1] = off + p1;
    sd[rl][lane*4+2] = off + p2; sd[rl][lane*4+3] = off + p3;
  }
  __syncthreads();
  const int j = tid;
  double* Sp = S + (size_t)b * NN * NN + (size_t)(s * 32) * NN + j;
  double sum = 0.0;
  for (int r = 0; r < 32; r += 8) {
    double v0 = sd[r+0][j], v1 = sd[r+1][j], v2 = sd[r+2][j], v3 = sd[r+3][j];
    double v4 = sd[r+4][j], v5 = sd[r+5][j], v6 = sd[r+6][j], v7 = sd[r+7][j];
    v0 += sum; v1 += v0; v2 += v1; v3 += v2; v4 += v3; v5 += v4; v6 += v5; v7 += v6;
    Sp[(size_t)(r+0)*NN] = v0; Sp[(size_t)(r+1)*NN] = v1;
    Sp[(size_t)(r+2)*NN] = v2; Sp[(size_t)(r+3)*NN] = v3;
    Sp[(size_t)(r+4)*NN] = v4; Sp[(size_t)(r+5)*NN] = v5;
    Sp[(size_t)(r+6)*NN] = v6; Sp[(size_t)(r+7)*NN] = v7;
    sum = v7;
  }
  aux[((size_t)b * 8 + s) * NN + j] = sum;
}

// ---------------- Ds -> A (shifted), C0 -> Cstk[0], out init -------------------
// S holds slab-local scans; cross-slab column offsets P (exclusive prefix of
// aux) are built in LDS and added on the fly: S_full[r][j] = S[r][j]+P[r>>5][j].
// Ds[n,j] (j>=n) = S_full[j][j] - 2*S_full[n-1][j] + S_full[n-1][n-1]
__global__ __launch_bounds__(256) void ds_mat(
    const double* __restrict__ S, const double* __restrict__ aux,
    float* __restrict__ A, float* __restrict__ Cstk, float* __restrict__ out)
{
  const int slab = blockIdx.x;          // 16 rows
  const int b = blockIdx.y;
  const double* Sb = S + (size_t)b * NN * NN;
  float* Ab = A + (size_t)b * NN * NN;
  const int tid = threadIdx.x;
  const int w = tid >> 6, lane = tid & 63;
  __shared__ double P[8][NN];           // 16 KB exclusive column prefixes
  __shared__ double diag[NN];
  {
    const double* ax = aux + (size_t)b * 8 * NN + tid;
    double run = 0.0;
    #pragma unroll
    for (int u = 0; u < 8; u++) { P[u][tid] = run; run += ax[(size_t)u * NN]; }
  }
  __syncthreads();
  diag[tid] = Sb[(size_t)tid * NN + tid] + P[tid >> 5][tid];
  __syncthreads();
  #pragma unroll
  for (int t = 0; t < 4; t++) {
    const int n = slab * 16 + w * 4 + t;
    const double snn = (n > 0) ? diag[n-1] : 0.0;
    const double* srow = Sb + (size_t)(n > 0 ? n-1 : 0) * NN;
    const double* Pr   = P[(n > 0 ? n-1 : 0) >> 5];
    #pragma unroll
    for (int c = 0; c < 4; c++) {
      const int jx = c * 64 + lane;
      float ds = INF;
      if (jx >= n) {
        const double sv = (n > 0) ? (srow[jx] + Pr[jx]) : 0.0;
        ds = (float)(diag[jx] - 2.0 * sv + snn);
      }
      if (jx < NN - 1) Ab[(size_t)n * NN + jx + 1] = ds;
      else             Cstk[(size_t)b * 32 * NN + n] = ds;   // Ds[n][N-1]
      if (jx == 0)     Ab[(size_t)n * NN + 0] = INF;
    }
  }
  if (slab == 0) out[b * NN + tid] = (tid == NN - 1) ? 1.0f : 0.0f;
}

// ---------------- min-plus MM: C = P (x) Q, 64x64 tile, per batch --------------
// P, Q strictly upper triangular (INF below): skip lower tiles + clamp k range.
__global__ __launch_bounds__(256) void mp_mm(
    const float* __restrict__ P, const float* __restrict__ Q, float* __restrict__ Cm)
{
  const int b = blockIdx.z;
  const int tid = threadIdx.x;
  const int tx = tid & 15;
  const int ty = tid >> 4;
  const int rowBase = blockIdx.y * 64;
  const int colBase = blockIdx.x * 64;
  float* Cb = Cm + (size_t)b * NN * NN;
  if (colBase < rowBase) {             // strictly-lower tile: all INF
    #pragma unroll
    for (int i = 0; i < 4; i++)
      #pragma unroll
      for (int j = 0; j < 4; j++)
        Cb[(size_t)(rowBase + ty*4 + i) * NN + (colBase + tx*4 + j)] = INF;
    return;
  }
  const float* Pb = P + (size_t)b * NN * NN;
  const float* Qb = Q + (size_t)b * NN * NN;
  __shared__ float As[16][64];
  __shared__ float Bs[16][64];
  float acc[4][4];
  #pragma unroll
  for (int i = 0; i < 4; i++)
    #pragma unroll
    for (int j = 0; j < 4; j++) acc[i][j] = INF;
  const int kHi = (colBase + 64 < NN) ? colBase + 64 : NN;
  for (int k0 = rowBase; k0 < kHi; k0 += 16) {
    {
      const int r  = tid >> 2;
      const int kq = (tid & 3) << 2;
      const float4 av = *(const float4*)(Pb + (size_t)(rowBase + r) * NN + (k0 + kq));
      As[kq+0][r] = av.x; As[kq+1][r] = av.y; As[kq+2][r] = av.z; As[kq+3][r] = av.w;
      const int kr = tid >> 4;
      const int c4 = (tid & 15) << 2;
      const float4 bv = *(const float4*)(Qb + (size_t)(k0 + kr) * NN + (colBase + c4));
      Bs[kr][c4+0] = bv.x; Bs[kr][c4+1] = bv.y; Bs[kr][c4+2] = bv.z; Bs[kr][c4+3] = bv.w;
    }
    __syncthreads();
    #pragma unroll
    for (int kk = 0; kk < 16; kk++) {
      const float4 a = *(const float4*)&As[kk][ty*4];
      const float4 bq = *(const float4*)&Bs[kk][tx*4];
      const float ar[4] = {a.x, a.y, a.z, a.w};
      const float br[4] = {bq.x, bq.y, bq.z, bq.w};
      #pragma unroll
      for (int i = 0; i < 4; i++)
        #pragma unroll
        for (int j = 0; j < 4; j++)
          acc[i][j] = fminf(acc[i][j], ar[i] + br[j]);
    }
    __syncthreads();
  }
  #pragma unroll
  for (int i = 0; i < 4; i++)
    #pragma unroll
    for (int j = 0; j < 4; j++)
      Cb[(size_t)(rowBase + ty*4 + i) * NN + (colBase + tx*4 + j)] =
          fminf(acc[i][j], INF);
}

// ---------------- full chain C_1..C_29 in one kernel: 1 block/batch ------------
// A4 segment per thread (<=16 float4, statically indexed/masked) is read by ONLY
// that thread across all 7 A4 stages -> hold it in VGPRs loaded straight from
// global; no LDS staging at all. Stages read just the C ring from LDS.
// C vectors live in an 8-slot ring (stage t reads (4t..4t+3)&7, writes +4..+7).
constexpr int CSTR = 260;    // ring stride: 16B-aligned, breaks pow2 banks
constexpr int RING = 8;      // ring depth (power of 2)

template<int W>
__device__ __forceinline__ void mp_stage_g(
    const float* __restrict__ P, size_t mb, int n, int q,
    const float* cs, int kin, float* outm)
{
  const float* Pr = P + mb + (size_t)n * NN + q * 64;
  float m[W];
  #pragma unroll
  for (int v = 0; v < W; v++) m[v] = INF;
  if (q * 64 + 63 > n) {          // chunk contains some j > n (else all INF)
    #pragma unroll 4
    for (int i = 0; i < 16; i++) {
      const float4 a = *(const float4*)(Pr + i * 4);
      #pragma unroll
      for (int v = 0; v < W; v++) {
        const float4 c = *(const float4*)&cs[((kin + v) & (RING-1)) * CSTR + q * 64 + i * 4];
        m[v] = fminf(m[v], fminf(fminf(a.x + c.x, a.y + c.y),
                                 fminf(a.z + c.z, a.w + c.w)));
      }
    }
  }
  #pragma unroll
  for (int v = 0; v < W; v++) {
    m[v] = fminf(m[v], __shfl_xor(m[v], 1));
    m[v] = fminf(m[v], __shfl_xor(m[v], 2));
    outm[v] = fminf(m[v], INF);
  }
}

__global__ __launch_bounds__(1024) void chain_full(
    const float* __restrict__ A, const float* __restrict__ A2,
    const float* __restrict__ A4, float* __restrict__ Cstk)
{
  const int b = blockIdx.x;
  const int tid = threadIdx.x;
  const int n = tid >> 2, q = tid & 3;
  __shared__ __align__(16) float cs[RING * CSTR];    // 8.3 KB (only LDS left)
  float* Ck = Cstk + (size_t)b * 32 * NN;
  const size_t mb = (size_t)b * NN * NN;

  const int ga  = n >> 2;
  const int La  = 252 - 4 * ga;        // finite floats in row n from jj0 (0: ga=63)
  const int jj0 = 4 * ga + 4;          // first float4-aligned finite jj

  // ---- prefetch this thread's A4 segment into registers (masked, static idx) --
  float4 areg[16];
  {
    const float* a4r = A4 + mb + (size_t)n * NN + jj0;
    #pragma unroll
    for (int fi = 0; fi < 16; fi++) {
      const int f = 4 * q + 16 * fi;
      if (f < La) areg[fi] = *(const float4*)(a4r + f);
      else        areg[fi] = make_float4(INF, INF, INF, INF);
    }
  }

  if (tid < NN) cs[tid] = Ck[tid];     // ring slot 0 = C0
  __syncthreads();

  float m1[1];
  mp_stage_g<1>(A, mb, n, q, cs, 0, m1);
  if (q == 0) { cs[1 * CSTR + n] = m1[0]; Ck[1 * NN + n] = m1[0]; }
  __syncthreads();

  float m2[2];
  mp_stage_g<2>(A2, mb, n, q, cs, 0, m2);
  if (q == 0) {
    cs[2 * CSTR + n] = m2[0]; Ck[2 * NN + n] = m2[0];
    cs[3 * CSTR + n] = m2[1]; Ck[3 * NN + n] = m2[1];
  }
  __syncthreads();

  for (int t = 0; t < 7; t++) {
    float m4[4];
    #pragma unroll
    for (int v = 0; v < 4; v++) m4[v] = INF;
    const float* c0 = cs + ((4*t + 0) & (RING-1)) * CSTR + jj0 + 4*q;
    const float* c1 = cs + ((4*t + 1) & (RING-1)) * CSTR + jj0 + 4*q;
    const float* c2 = cs + ((4*t + 2) & (RING-1)) * CSTR + jj0 + 4*q;
    const float* c3 = cs + ((4*t + 3) & (RING-1)) * CSTR + jj0 + 4*q;
    #pragma unroll
    for (int fi = 0; fi < 16; fi++) {
      const int f = 4 * q + 16 * fi;
      if (f < La) {
        const float4 a = areg[fi];
        const float4 cA = *(const float4*)(c0 + 16 * fi);
        const float4 cB = *(const float4*)(c1 + 16 * fi);
        const float4 cC = *(const float4*)(c2 + 16 * fi);
        const float4 cD = *(const float4*)(c3 + 16 * fi);
        m4[0] = fminf(m4[0], fminf(fminf(a.x + cA.x, a.y + cA.y),
                                   fminf(a.z + cA.z, a.w + cA.w)));
        m4[1] = fminf(m4[1], fminf(fminf(a.x + cB.x, a.y + cB.y),
                                   fminf(a.z + cB.z, a.w + cB.w)));
        m4[2] = fminf(m4[2], fminf(fminf(a.x + cC.x, a.y + cC.y),
                                   fminf(a.z + cC.z, a.w + cC.w)));
        m4[3] = fminf(m4[3], fminf(fminf(a.x + cD.x, a.y + cD.y),
                                   fminf(a.z + cD.z, a.w + cD.w)));
      }
    }
    #pragma unroll
    for (int v = 0; v < 4; v++) {
      m4[v] = fminf(m4[v], __shfl_xor(m4[v], 1));
      m4[v] = fminf(m4[v], __shfl_xor(m4[v], 2));
      m4[v] = fminf(m4[v], INF);
    }
    if (q == 0) {
      #pragma unroll
      for (int v = 0; v < 4; v++) {
        const int k = 4 * t + 4 + v;
        cs[(k & (RING-1)) * CSTR + n] = m4[v];
        Ck[k * NN + n] = m4[v];
      }
    }
    __syncthreads();
  }
}

// ---------------- fused softmax: row sums (LDS) + column accumulation ----------
// One block per (k,b): phase 1 computes invs for all 256 rows into LDS
// (4 threads/row x 4 row-groups), phase 2 is the column pass. Removes the
// sm_rows dispatch and the invs global round-trip.
__global__ __launch_bounds__(256) void sm_fused(
    const float* __restrict__ A, const float* __restrict__ Cstk,
    float* __restrict__ out)
{
  const int k = blockIdx.x + 1;        // 1..29
  const int b = blockIdx.y;
  const int limit = NN - k;
  const int tid = threadIdx.x;
  const float* Ab  = A + (size_t)b * NN * NN;
  const float* Ckb = Cstk + (size_t)b * 32 * NN;
  __shared__ __align__(16) float cprev[NN];   // C_{k-1}
  __shared__ float ck[NN];                    // C_k
  __shared__ float ivh[NN];                   // 1/s per row
  cprev[tid] = Ckb[(k - 1) * NN + tid];
  ck[tid]    = Ckb[k * NN + tid];
  __syncthreads();
  const int r = tid >> 2, q = tid & 3;
  #pragma unroll
  for (int rg = 0; rg < 4; rg++) {
    const int n = rg * 64 + r;
    const float m = ck[n];
    const float* Ar = Ab + (size_t)n * NN + q * 64;
    float s = 0.f;
    if (q * 64 + 63 > n) {              // chunk has some jj > n
      #pragma unroll 4
      for (int i = 0; i < 16; i++) {
        const float4 a = *(const float4*)(Ar + i * 4);
        const int jj = q * 64 + i * 4;
        const float4 c = *(const float4*)&cprev[jj];
        s += (jj + 0 <= limit) ? __expf(m - a.x - c.x) : 0.f;
        s += (jj + 1 <= limit) ? __expf(m - a.y - c.y) : 0.f;
        s += (jj + 2 <= limit) ? __expf(m - a.z - c.z) : 0.f;
        s += (jj + 3 <= limit) ? __expf(m - a.w - c.w) : 0.f;
      }
    }
    s += __shfl_xor(s, 1);
    s += __shfl_xor(s, 2);
    if (q == 0) ivh[n] = 1.0f / s;
  }
  __syncthreads();
  const int j = tid;
  if (j < limit) {
    const float cj = cprev[j + 1];
    const int nmax = (j < limit - 1) ? j : limit - 1;
    float a = 0.0f;
    #pragma unroll 4
    for (int nr = 0; nr <= nmax; nr++)
      a += __expf(ck[nr] - Ab[(size_t)nr * NN + j + 1] - cj) * ivh[nr];
    int kmaxj = NN - 1 - j; if (kmaxj > KMAX - 1) kmaxj = KMAX - 1;
    const float cnt = (float)((j + 1) * kmaxj);
    atomicAdd(&out[b * NN + j], a / cnt);
  }
}

extern "C" void kernel_launch(void* const* d_in, const int* in_sizes, int n_in,
                              void* d_out, int out_size, void* d_ws, size_t ws_size,
                              hipStream_t stream) {
  const float* x  = (const float*)d_in[0];
  const float* W0 = (const float*)d_in[1];
  const float* b0 = (const float*)d_in[2];
  const float* W1 = (const float*)d_in[3];
  const float* b1 = (const float*)d_in[4];
  float* out = (float*)d_out;

  // ws layout (max 7 MiB + 128 KiB used; ws proven >= 8 MiB):
  //  region        lifetime
  //  h    [0,2M)   gemm1 W -> gemm2 R
  //  S    [0,4M)   scan_slab W (h dead) -> ds_mat R        (slab-local scans)
  //  A2   [0,2M)   mp_mm1 W (S dead) -> mp_mm2/chain R
  //  A4   [2M,4M)  mp_mm2 W -> chain R
  //  D    [4M,6M)  corr_dist W -> scan_slab R
  //  A    [4M,6M)  ds_mat W (D dead) -> mp_mm1/chain/sm R
  //  z    [6M,7M)  gemm2 W -> corr_dist R
  //  Cstk [6M,6.25M) ds_mat W (z dead) -> chain RW -> sm R
  //  aux  [7M,7M+128K) scan_slab W -> ds_mat R
  char* base = (char*)d_ws;
  float*  h    = (float*)(base);
  double* S    = (double*)(base);
  float*  A2   = (float*)(base);
  float*  A4   = (float*)(base + (2u << 20));
  float*  D    = (float*)(base + (4u << 20));
  float*  A    = (float*)(base + (4u << 20));
  float*  z    = (float*)(base + (6u << 20));
  float*  Cstk = (float*)(base + (6u << 20));
  double* aux  = (double*)(base + (7u << 20));

  gemm_bias_act<<<dim3(F1/32, ROWS/64), 256, 0, stream>>>(x, W0, b0, h, ROWS, F1, F0, 1);
  gemm_bias_act<<<dim3(F2/32, ROWS/64), 256, 0, stream>>>(h, W1, b1, z, ROWS, F2, F1, 0);
  corr_dist<<<dim3(NN/64, NN/64, NB), 256, 0, stream>>>(z, D);
  scan_slab<<<dim3(NB*8), 256, 0, stream>>>(D, S, aux);
  ds_mat<<<dim3(16, NB), 256, 0, stream>>>(S, aux, A, Cstk, out);
  mp_mm<<<dim3(NN/64, NN/64, NB), 256, 0, stream>>>(A, A, A2);
  mp_mm<<<dim3(NN/64, NN/64, NB), 256, 0, stream>>>(A2, A2, A4);
  chain_full<<<dim3(NB), 1024, 0, stream>>>(A, A2, A4, Cstk);
  sm_fused<<<dim3(KMAX-1, NB), 256, 0, stream>>>(A, Cstk, out);
}